// Round 3
// baseline (423.396 us; speedup 1.0000x reference)
//
#include <hip/hip_runtime.h>

typedef __bf16 bf16;
typedef __bf16 bf16x8 __attribute__((ext_vector_type(8)));
typedef float  f32x4  __attribute__((ext_vector_type(4)));

#define DIM   1024
#define NH    16
#define NKV   4
#define HD    64
#define SLEN  264
#define BTOT  64            // B*T
#define MROWS (BTOT * SLEN) // 16896
#define NQKV  1536          // 1024 q + 256 k + 256 v
#define NZ    256
#define VPAD  288           // padded key dim of vt

// ---------------- async global->LDS (wave-uniform LDS base + lane*16; global src is per-lane) ----------------
__device__ __forceinline__ void gl_lds16(const bf16* g, bf16* l) {
    __builtin_amdgcn_global_load_lds((__attribute__((address_space(1))) void*)(g),
                                     (__attribute__((address_space(3))) void*)(l),
                                     16, 0, 0);
}

// ---------------- f32 -> bf16 converters ----------------
__global__ void cvt_f32_bf16(const float* __restrict__ src, bf16* __restrict__ dst, int n) {
    int i = (blockIdx.x * 256 + threadIdx.x) * 4;
    if (i < n) {
        float4 v = *(const float4*)(src + i);
        dst[i + 0] = (bf16)v.x; dst[i + 1] = (bf16)v.y;
        dst[i + 2] = (bf16)v.z; dst[i + 3] = (bf16)v.w;
    }
}

__global__ void cvt_wcat(const float* __restrict__ wq, const float* __restrict__ wk,
                         const float* __restrict__ wv, bf16* __restrict__ dst) {
    int i = (blockIdx.x * 256 + threadIdx.x) * 4;   // total 1536*1024
    const float* src; int off;
    if (i < 1024 * 1024)      { src = wq; off = i; }
    else if (i < 1280 * 1024) { src = wk; off = i - 1024 * 1024; }
    else                      { src = wv; off = i - 1280 * 1024; }
    float4 v = *(const float4*)(src + off);
    dst[i + 0] = (bf16)v.x; dst[i + 1] = (bf16)v.y;
    dst[i + 2] = (bf16)v.z; dst[i + 3] = (bf16)v.w;
}

// ---------------- RoPE cos/sin table: ctab[s][d] for d in 0..31 (period-32 in head dim) ----------------
__global__ void rope_tab_kernel(float2* __restrict__ ctab) {
    int i = blockIdx.x * 256 + threadIdx.x;   // 8192 = 256 x 32
    int s = i >> 5, d = i & 31;
    const float LN1 = 0.5756462732485115f;    // ln(10000)/16
    float pos = (d < 16) ? (float)(s >> 4) : (float)(s & 15);
    float ang = pos * expf(-(float)(d & 15) * LN1);
    float sn, cs; sincosf(ang, &sn, &cs);
    ctab[i] = make_float2(cs, sn);
}

// bijective XCD-chunked block swizzle (m204): contiguous wg-chunks per XCD
__device__ __forceinline__ int xcd_swizzle(int orig, int nwg) {
    int q = nwg >> 3, r = nwg & 7;
    int xcd = orig & 7, lid = orig >> 3;
    return (xcd < r ? xcd * (q + 1) : r * (q + 1) + (xcd - r) * q) + lid;
}

// ================= 256x256 BK=32 2-deep core, 64 KiB LDS -> 2 blocks/CU =================
// 512 threads = 8 waves (2M x 4N); per-wave C = 2 a-halves x 64x64 = acc[2][4][4].
// Row map (matches epilogue): tile row R = a*128 + wm*64 + i*16 + r16.
// LDS: A0,A1,B0,B1 each 16KB = one 256x32 bf16 K-tile, PACKED [128][64]:
//   logical (R,k) -> phys row p = R>>1, chunk s_phys = ((R&1)*4 + (k>>3)) ^ (p&7)
//   -> 128B phys rows (row-invariant banks) + XOR swizzle = conflict-free frag
//   reads (per quad-group: 16 lanes over 8 slots = 2-way = free).
// Stage: site s in {0,1} covers phys rows [s*64,+64) = logical half [s*128,+128);
// one gl_lds16 per site: wave w writes 1KB at (s*4096 + w*512), per-lane global
// src carries the inverse permutation.
// Phase a reads A site a + all of B. Per phase: 8 ds_read_b128 + 2 stage insts
// + barrier + lgkmcnt(0) + setprio(1) + 16 MFMA + setprio(0) + barrier.
// Stage schedule for tile t (parity d), staging tile t+1 / t+2:
//   ph(t,0): STA(A[d^1],s1,t+1), STB(B[d^1],s0,t+1)            [both dead since ph(t-1,1)]
//   ph(t,1): STB(B[d^1],s1,t+1), STA(A[d],s0,t+2), GATE vmcnt(1)
//     - A[d] s0 was read in ph(t,0) (done); ph(t,1) reads s1 only -> disjoint.
//     - vmcnt(1): all stages except the just-issued A[t+2]-s0 have landed
//       before the barrier -> counted gate, never vmcnt(0) in the loop.
// Tail: t+1/t+2 clamped to 31 = dummy re-stages into dead/disjoint regions.

#define GATE1  asm volatile("s_waitcnt vmcnt(1)" ::: "memory")
#define NOGATE do {} while (0)

#define STA(DBUF, SITE, KT) gl_lds16(Asrc[SITE] + (KT) * 32, (DBUF) + (SITE) * 4096 + wid * 512)
#define STB(DBUF, SITE, KT) gl_lds16(Bsrc[SITE] + (KT) * 32, (DBUF) + (SITE) * 4096 + wid * 512)

#define PHASE(Ad, Bd, AA, GATE_STMT, ...) do {                                 \
    bf16x8 af_[4], bf_[4];                                                     \
    _Pragma("unroll")                                                          \
    for (int i_ = 0; i_ < 4; i_++) {                                           \
        af_[i_] = *(const bf16x8*)((Ad) + aOff[AA][i_]);                       \
        bf_[i_] = *(const bf16x8*)((Bd) + bOff[i_]);                           \
    }                                                                          \
    __VA_ARGS__;                                                               \
    GATE_STMT;                                                                 \
    __builtin_amdgcn_s_barrier();                                              \
    asm volatile("s_waitcnt lgkmcnt(0)" ::: "memory");                         \
    __builtin_amdgcn_sched_barrier(0);                                         \
    __builtin_amdgcn_s_setprio(1);                                             \
    _Pragma("unroll")                                                          \
    for (int i_ = 0; i_ < 4; i_++)                                             \
        _Pragma("unroll")                                                      \
        for (int n_ = 0; n_ < 4; n_++)                                         \
            acc[AA][i_][n_] = __builtin_amdgcn_mfma_f32_16x16x32_bf16(         \
                af_[i_], bf_[n_], acc[AA][i_][n_], 0, 0, 0);                   \
    __builtin_amdgcn_s_setprio(0);                                             \
    __builtin_amdgcn_s_barrier();                                              \
} while (0)

__device__ __forceinline__ void gemm256_core(const bf16* __restrict__ Ag,
                                             const bf16* __restrict__ Bg,
                                             f32x4 (&acc)[2][4][4]) {
    __shared__ __align__(16) bf16 A0[8192], A1[8192], B0[8192], B1[8192];

    const int tid  = threadIdx.x;
    const int wid  = tid >> 6, lane = tid & 63;
    const int quad = lane >> 4, r16 = lane & 15;
    const int wm = wid & 1, wn = wid >> 1;

    // stage source: site s, wave wid, lane -> phys row p, slot s_phys;
    // invert the read swizzle so linear LDS writes carry logical data.
    const bf16* Asrc[2]; const bf16* Bsrc[2];
#pragma unroll
    for (int s = 0; s < 2; s++) {
        int p  = s * 64 + wid * 8 + (lane >> 3);
        int sl = (lane & 7) ^ (p & 7);              // logical slot
        int R  = (p << 1) | (sl >> 2);
        int kc = sl & 3;
        Asrc[s] = Ag + (size_t)R * DIM + kc * 8;
        Bsrc[s] = Bg + (size_t)R * DIM + kc * 8;
    }

    // frag read offsets (elements): R = a*128 + wm*64 + i*16 + r16 (A),
    //                               R = wn*64 + n*16 + r16        (B)
    int aOff[2][4], bOff[4];
#pragma unroll
    for (int a = 0; a < 2; a++)
#pragma unroll
        for (int i = 0; i < 4; i++) {
            int R = a * 128 + wm * 64 + i * 16 + r16;
            int p = R >> 1;
            int sp = (((R & 1) * 4 + quad) ^ (p & 7));
            aOff[a][i] = p * 64 + sp * 8;
        }
#pragma unroll
    for (int n = 0; n < 4; n++) {
        int R = wn * 64 + n * 16 + r16;
        int p = R >> 1;
        int sp = (((R & 1) * 4 + quad) ^ (p & 7));
        bOff[n] = p * 64 + sp * 8;
    }

    // prologue: tile0 complete + tile1 site0-of-A; gate to <=1 outstanding.
    STA(A0, 0, 0); STA(A0, 1, 0);
    STB(B0, 0, 0); STB(B0, 1, 0);
    STA(A1, 0, 1);
    GATE1;
    __builtin_amdgcn_s_barrier();

#pragma unroll 1
    for (int it = 0; it < 16; ++it) {       // 2 K-tiles/iter, NT = 32
        const int u1 = 2 * it + 1;
        int u2 = 2 * it + 2; if (u2 > 31) u2 = 31;
        int u3 = 2 * it + 3; if (u3 > 31) u3 = 31;
        // tile 2it (parity 0):
        PHASE(A0, B0, 0, NOGATE, STA(A1, 1, u1), STB(B1, 0, u1));
        PHASE(A0, B0, 1, GATE1,  STB(B1, 1, u1), STA(A0, 0, u2));
        // tile 2it+1 (parity 1):
        PHASE(A1, B1, 0, NOGATE, STA(A0, 1, u2), STB(B0, 0, u2));
        PHASE(A1, B1, 1, GATE1,  STB(B0, 1, u2), STA(A1, 0, u3));
    }
}

// ---------------- QKV GEMM with fused QKNorm + partial 2D-RoPE epilogue ----------------
// C[M,1536] = A[M,1024] @ W[1536,1024]^T. Each wave's 64 cols == one head.
__global__ __launch_bounds__(512) void gemm_qkv(const bf16* __restrict__ A,
                                                const bf16* __restrict__ Bw,
                                                bf16* __restrict__ out,
                                                const float* __restrict__ qw,
                                                const float* __restrict__ kw,
                                                const float2* __restrict__ ctab) {
    const int nwg = (MROWS / 256) * (NQKV / 256);   // 396
    int wg = xcd_swizzle(blockIdx.x, nwg);
    const int bm = wg / 6, bn = wg - bm * 6;

    f32x4 acc[2][4][4];
#pragma unroll
    for (int a = 0; a < 2; a++)
#pragma unroll
        for (int i = 0; i < 4; i++)
#pragma unroll
            for (int n = 0; n < 4; n++) acc[a][i][n] = (f32x4){0.f, 0.f, 0.f, 0.f};

    gemm256_core(A + (size_t)bm * 256 * DIM, Bw + (size_t)bn * 256 * DIM, acc);

    const int tid  = threadIdx.x;
    const int wid  = tid >> 6, lane = tid & 63;
    const int quad = lane >> 4, r16 = lane & 15;
    const int wm = wid & 1, wn = wid >> 1;
    const int colbase = bn * 256 + wn * 64;          // 64-aligned -> one head per wave
    const int rowb    = bm * 256 + wm * 64;

    if (bn < 5) {
        const float* w = (bn < 4) ? qw : kw;
        float wreg[4];
#pragma unroll
        for (int n = 0; n < 4; n++) wreg[n] = w[n * 16 + r16];
#pragma unroll
        for (int a = 0; a < 2; a++)
#pragma unroll
            for (int i = 0; i < 4; i++)
#pragma unroll
                for (int r = 0; r < 4; r++) {
                    float ss = 0.f;
#pragma unroll
                    for (int n = 0; n < 4; n++) ss += acc[a][i][n][r] * acc[a][i][n][r];
                    ss += __shfl_xor(ss, 1, 64);
                    ss += __shfl_xor(ss, 2, 64);
                    ss += __shfl_xor(ss, 4, 64);
                    ss += __shfl_xor(ss, 8, 64);
                    float rms = rsqrtf(ss * (1.f / 64.f) + 1e-6f);
                    float xv[4];
#pragma unroll
                    for (int n = 0; n < 4; n++) xv[n] = acc[a][i][n][r] * rms * wreg[n];
                    int gm = rowb + a * 128 + i * 16 + quad * 4 + r;
                    int s = gm % SLEN;
                    if (s < NZ) {   // partial 2D RoPE; pairs (n, n+2) are lane-local
                        float2 cs0 = ctab[s * 32 + r16];
                        float2 cs1 = ctab[s * 32 + 16 + r16];
                        float a0 = xv[0] * cs0.x - xv[2] * cs0.y;
                        float a2 = xv[2] * cs0.x + xv[0] * cs0.y;
                        float a1 = xv[1] * cs1.x - xv[3] * cs1.y;
                        float a3 = xv[3] * cs1.x + xv[1] * cs1.y;
                        xv[0] = a0; xv[1] = a1; xv[2] = a2; xv[3] = a3;
                    }
                    size_t rowoff = (size_t)gm * NQKV + colbase + r16;
#pragma unroll
                    for (int n = 0; n < 4; n++) out[rowoff + n * 16] = (bf16)xv[n];
                }
    } else {
#pragma unroll
        for (int a = 0; a < 2; a++)
#pragma unroll
            for (int i = 0; i < 4; i++)
#pragma unroll
                for (int r = 0; r < 4; r++) {
                    int gm = rowb + a * 128 + i * 16 + quad * 4 + r;
                    size_t rowoff = (size_t)gm * NQKV + colbase + r16;
#pragma unroll
                    for (int n = 0; n < 4; n++) out[rowoff + n * 16] = (bf16)acc[a][i][n][r];
                }
    }
}

// ---------------- O-projection GEMM: C[M,1024]=A@B^T, f32 out, same 256x256 core ----------------
__global__ __launch_bounds__(512) void gemm_bt(const bf16* __restrict__ A,
                                               const bf16* __restrict__ Bw,
                                               float* __restrict__ Cout) {
    const int nwg = (MROWS / 256) * (DIM / 256);    // 264
    int wg = xcd_swizzle(blockIdx.x, nwg);
    const int bm = wg / 4, bn = wg - bm * 4;

    f32x4 acc[2][4][4];
#pragma unroll
    for (int a = 0; a < 2; a++)
#pragma unroll
        for (int i = 0; i < 4; i++)
#pragma unroll
            for (int n = 0; n < 4; n++) acc[a][i][n] = (f32x4){0.f, 0.f, 0.f, 0.f};

    gemm256_core(A + (size_t)bm * 256 * DIM, Bw + (size_t)bn * 256 * DIM, acc);

    const int tid  = threadIdx.x;
    const int wid  = tid >> 6, lane = tid & 63;
    const int quad = lane >> 4, r16 = lane & 15;
    const int wm = wid & 1, wn = wid >> 1;
    const int colbase = bn * 256 + wn * 64;
    const int rowb    = bm * 256 + wm * 64;
#pragma unroll
    for (int a = 0; a < 2; a++)
#pragma unroll
        for (int i = 0; i < 4; i++)
#pragma unroll
            for (int r = 0; r < 4; r++) {
                int gm = rowb + a * 128 + i * 16 + quad * 4 + r;
                size_t rowoff = (size_t)gm * DIM + colbase + r16;
#pragma unroll
                for (int n = 0; n < 4; n++) Cout[rowoff + n * 16] = acc[a][i][n][r];
            }
}

// ---------------- V transpose: qkv V region -> vt[(bt,kv)][d][key], zero-padded to 288 keys ----------------
__global__ __launch_bounds__(256) void vtrans_kernel(const bf16* __restrict__ qkv,
                                                     bf16* __restrict__ vt) {
    __shared__ bf16 Ls[64 * 272];
    const int tid = threadIdx.x;
    const int b = blockIdx.x, bt = b >> 2, kv = b & 3;
    const int part = tid >> 5;      // 0..7 (dim octet)
    const int rr   = tid & 31;      // row within pass
#pragma unroll
    for (int pass = 0; pass < 9; ++pass) {
        int row = pass * 32 + rr;
        if (row < SLEN) {
            bf16x8 v = *(const bf16x8*)(qkv + (size_t)(bt * SLEN + row) * NQKV + 1280 + kv * 64 + part * 8);
#pragma unroll
            for (int j = 0; j < 8; j++) Ls[(part * 8 + j) * 272 + row] = v[j];
        }
    }
    __syncthreads();
    const int d = tid >> 2, seg = tid & 3;
    size_t obase = ((size_t)b * 64 + d) * VPAD;
#pragma unroll
    for (int m = 0; m < 9; ++m) {
        int col = seg * 72 + m * 8;
        bf16x8 o;
#pragma unroll
        for (int j = 0; j < 8; j++) {
            int s = col + j;
            o[j] = (s < SLEN) ? Ls[d * 272 + s] : (bf16)0.f;
        }
        *(bf16x8*)(vt + obase + col) = o;
    }
}

// ---------------- attention v4: one wave per (32-row qtile-pair, head, bt) ----------------
// K prefetched one chunk ahead; softcap via odd-poly tanh (|z|<=0.16) + single exp2.
__global__ __launch_bounds__(256) void attn_kernel(const bf16* __restrict__ qkv,
                                                   const bf16* __restrict__ vt,
                                                   bf16* __restrict__ aout) {
    const int PLD = 40;
    __shared__ __align__(16) bf16 Pb[4][2][16 * PLD];   // per-wave, per-qtile P buffers

    const int tid = threadIdx.x;
    const int wid = tid >> 6, lane = tid & 63;
    const int quad = lane >> 4, r16 = lane & 15;
    const int qp = blockIdx.x;           // 0..8 (9 pairs of 16-row tiles = 288 rows)
    const int kv = blockIdx.y, bt = blockIdx.z;
    const int h = kv * 4 + wid;

    // Q A-fragments for two 16-row tiles
    bf16x8 qa[2][2];
#pragma unroll
    for (int qi = 0; qi < 2; qi++) {
        int q0 = qp * 32 + qi * 16 + r16;
        int qcl = q0 < SLEN ? q0 : SLEN - 1;
        const bf16* qb = qkv + (size_t)(bt * SLEN + qcl) * NQKV + h * HD + quad * 8;
        qa[qi][0] = *(const bf16x8*)qb;
        qa[qi][1] = *(const bf16x8*)(qb + 32);
    }

    f32x4 oacc[2][4];
    float lsum[2][4];
#pragma unroll
    for (int qi = 0; qi < 2; qi++)
#pragma unroll
        for (int i = 0; i < 4; i++) { oacc[qi][i] = (f32x4){0.f, 0.f, 0.f, 0.f}; lsum[qi][i] = 0.f; }

    const bf16* kbase = qkv + (size_t)bt * SLEN * NQKV + 1024 + kv * HD + quad * 8;
    const bf16* vbase = vt + (size_t)(bt * 4 + kv) * HD * VPAD;

    bf16x8 nk[2][2];
#pragma unroll
    for (int kt = 0; kt < 2; kt++) {
        int key = kt * 16 + r16;
        const bf16* kp = kbase + (size_t)key * NQKV;
        nk[kt][0] = *(const bf16x8*)kp;
        nk[kt][1] = *(const bf16x8*)(kp + 32);
    }

    for (int c = 0; c < 9; ++c) {
        bf16x8 ck[2][2];
#pragma unroll
        for (int kt = 0; kt < 2; kt++) { ck[kt][0] = nk[kt][0]; ck[kt][1] = nk[kt][1]; }
        if (c < 8) {   // prefetch next chunk's K
#pragma unroll
            for (int kt = 0; kt < 2; kt++) {
                int key = (c + 1) * 32 + kt * 16 + r16;
                int kc = key < SLEN ? key : SLEN - 1;
                const bf16* kp = kbase + (size_t)kc * NQKV;
                nk[kt][0] = *(const bf16x8*)kp;
                nk[kt][1] = *(const bf16x8*)(kp + 32);
            }
        }
        // V B-fragments (coalesced from vt; covered by QK+softcap latency)
        bf16x8 cv[4];
#pragma unroll
        for (int dt = 0; dt < 4; ++dt)
            cv[dt] = *(const bf16x8*)(vbase + (size_t)(dt * 16 + r16) * VPAD + c * 32 + quad * 8);

        // QK^T
        f32x4 s[2][2];
#pragma unroll
        for (int qi = 0; qi < 2; qi++)
#pragma unroll
            for (int kt = 0; kt < 2; kt++) {
                f32x4 t = (f32x4){0.f, 0.f, 0.f, 0.f};
                t = __builtin_amdgcn_mfma_f32_16x16x32_bf16(qa[qi][0], ck[kt][0], t, 0, 0, 0);
                t = __builtin_amdgcn_mfma_f32_16x16x32_bf16(qa[qi][1], ck[kt][1], t, 0, 0, 0);
                s[qi][kt] = t;
            }

        // softcap: p = exp(50*tanh(sc/400))  [|z|<=0.16 -> 5th-order odd poly, err<2e-7]
#pragma unroll
        for (int qi = 0; qi < 2; qi++) {
            bf16* Pw = &Pb[wid][qi][0];
#pragma unroll
            for (int kt = 0; kt < 2; kt++)
#pragma unroll
                for (int r = 0; r < 4; ++r) {
                    int key = c * 32 + kt * 16 + r16;
                    float sc = s[qi][kt][r];
                    float z = sc * 0.0025f;                       // sc*SCALE/50
                    float z2 = z * z;
                    float poly = fmaf(z2, fmaf(z2, 0.133333333f, -0.333333333f), 1.f);
                    float p = exp2f(sc * 0.18033688f * poly);     // 50*log2e*z*poly
                    p = (key < SLEN) ? p : 0.f;
                    bf16 pb = (bf16)p;
                    lsum[qi][r] += (float)pb;
                    Pw[(quad * 4 + r) * PLD + kt * 16 + r16] = pb;
                }
            // C-layout -> A-layout repack through per-wave LDS (wave-coherent, no barrier)
            bf16x8 pa = *(const bf16x8*)&Pw[r16 * PLD + quad * 8];
#pragma unroll
            for (int dt = 0; dt < 4; ++dt)
                oacc[qi][dt] = __builtin_amdgcn_mfma_f32_16x16x32_bf16(pa, cv[dt], oacc[qi][dt], 0, 0, 0);
        }
    }

    // finalize: reduce l across the 16 key-lanes, divide, store
#pragma unroll
    for (int qi = 0; qi < 2; qi++)
#pragma unroll
        for (int r = 0; r < 4; ++r) {
            float l = lsum[qi][r];
            l += __shfl_xor(l, 1, 64);
            l += __shfl_xor(l, 2, 64);
            l += __shfl_xor(l, 4, 64);
            l += __shfl_xor(l, 8, 64);
            float inv = 1.f / l;
            int q = qp * 32 + qi * 16 + quad * 4 + r;
            if (q < SLEN) {
                size_t base = (size_t)(bt * SLEN + q) * (NH * HD) + h * HD;
#pragma unroll
                for (int dt = 0; dt < 4; ++dt)
                    aout[base + dt * 16 + r16] = (bf16)(oacc[qi][dt][r] * inv);
            }
        }
}

// ---------------- launcher ----------------
extern "C" void kernel_launch(void* const* d_in, const int* in_sizes, int n_in,
                              void* d_out, int out_size, void* d_ws, size_t ws_size,
                              hipStream_t stream) {
    const float* x   = (const float*)d_in[0];
    const float* wq  = (const float*)d_in[1];
    const float* wk  = (const float*)d_in[2];
    const float* wv  = (const float*)d_in[3];
    const float* wo  = (const float*)d_in[4];
    const float* qnw = (const float*)d_in[5];
    const float* knw = (const float*)d_in[6];

    bf16* xbf  = (bf16*)d_ws;                        // 16896x1024 (reused as aout)
    bf16* wcat = xbf  + (size_t)MROWS * DIM;         // 1536x1024  [wq;wk;wv]
    bf16* wobf = wcat + (size_t)NQKV * DIM;          // 1024x1024
    bf16* qkv  = wobf + (size_t)DIM * DIM;           // 16896x1536
    bf16* vt   = qkv  + (size_t)MROWS * NQKV;        // 256x64x288
    float2* ctab = (float2*)(vt + (size_t)BTOT * NKV * HD * VPAD);  // 256x32
    bf16* aout = xbf;                                // xbf dead after gemm_qkv

    rope_tab_kernel<<<32, 256, 0, stream>>>(ctab);
    cvt_f32_bf16<<<(MROWS * DIM) / 1024, 256, 0, stream>>>(x, xbf, MROWS * DIM);
    cvt_wcat<<<(NQKV * DIM) / 1024, 256, 0, stream>>>(wq, wk, wv, wcat);
    cvt_f32_bf16<<<(DIM * DIM) / 1024, 256, 0, stream>>>(wo, wobf, DIM * DIM);

    gemm_qkv<<<(MROWS / 256) * (NQKV / 256), 512, 0, stream>>>(xbf, wcat, qkv, qnw, knw, ctab);
    vtrans_kernel<<<BTOT * NKV, 256, 0, stream>>>(qkv, vt);
    attn_kernel<<<dim3(9, NKV, BTOT), 256, 0, stream>>>(qkv, vt, aout);
    gemm_bt<<<(MROWS / 256) * (DIM / 256), 512, 0, stream>>>(aout, wobf, (float*)d_out);
}

// Round 4
// 338.574 us; speedup vs baseline: 1.2505x; 1.2505x over previous
//
#include <hip/hip_runtime.h>

typedef __bf16 bf16;
typedef __bf16 bf16x8 __attribute__((ext_vector_type(8)));
typedef float  f32x4  __attribute__((ext_vector_type(4)));
typedef float  f32x16 __attribute__((ext_vector_type(16)));
typedef unsigned int u32;

#define DIM   1024
#define NH    16
#define NKV   4
#define HD    64
#define SLEN  264
#define BTOT  64            // B*T
#define MROWS (BTOT * SLEN) // 16896
#define NQKV  1536          // 1024 q + 256 k + 256 v
#define NZ    256
#define VPAD  288           // padded key dim of vt

// ---------------- async global->LDS (wave-uniform LDS base + lane*16; global src is per-lane) ----------------
__device__ __forceinline__ void gl_lds16(const bf16* g, bf16* l) {
    __builtin_amdgcn_global_load_lds((__attribute__((address_space(1))) void*)(g),
                                     (__attribute__((address_space(3))) void*)(l),
                                     16, 0, 0);
}

// ---------------- f32 -> bf16 converter for x ----------------
__global__ void cvt_f32_bf16(const float* __restrict__ src, bf16* __restrict__ dst, int n) {
    int i = (blockIdx.x * 256 + threadIdx.x) * 4;
    if (i < n) {
        float4 v = *(const float4*)(src + i);
        dst[i + 0] = (bf16)v.x; dst[i + 1] = (bf16)v.y;
        dst[i + 2] = (bf16)v.z; dst[i + 3] = (bf16)v.w;
    }
}

// ---------------- fused prep: wcat cvt (1536 blk) + wo cvt (1024 blk) + rope tab (32 blk) ----------------
__global__ void prep_misc(const float* __restrict__ wq, const float* __restrict__ wk,
                          const float* __restrict__ wv, const float* __restrict__ wo,
                          bf16* __restrict__ wcat, bf16* __restrict__ wobf,
                          float2* __restrict__ ctab) {
    int b = blockIdx.x, tid = threadIdx.x;
    if (b < 1536) {
        int i = (b * 256 + tid) * 4;
        const float* src; int off;
        if (i < 1024 * 1024)      { src = wq; off = i; }
        else if (i < 1280 * 1024) { src = wk; off = i - 1024 * 1024; }
        else                      { src = wv; off = i - 1280 * 1024; }
        float4 v = *(const float4*)(src + off);
        wcat[i + 0] = (bf16)v.x; wcat[i + 1] = (bf16)v.y;
        wcat[i + 2] = (bf16)v.z; wcat[i + 3] = (bf16)v.w;
    } else if (b < 2560) {
        int i = ((b - 1536) * 256 + tid) * 4;
        float4 v = *(const float4*)(wo + i);
        wobf[i + 0] = (bf16)v.x; wobf[i + 1] = (bf16)v.y;
        wobf[i + 2] = (bf16)v.z; wobf[i + 3] = (bf16)v.w;
    } else {
        int i = (b - 2560) * 256 + tid;    // 8192 = 256 x 32
        int s = i >> 5, d = i & 31;
        const float LN1 = 0.5756462732485115f;    // ln(10000)/16
        float pos = (d < 16) ? (float)(s >> 4) : (float)(s & 15);
        float ang = pos * expf(-(float)(d & 15) * LN1);
        float sn, cs; sincosf(ang, &sn, &cs);
        ctab[i] = make_float2(cs, sn);
    }
}

// bijective XCD-chunked block swizzle (m204): contiguous wg-chunks per XCD
__device__ __forceinline__ int xcd_swizzle(int orig, int nwg) {
    int q = nwg >> 3, r = nwg & 7;
    int xcd = orig & 7, lid = orig >> 3;
    return (xcd < r ? xcd * (q + 1) : r * (q + 1) + (xcd - r) * q) + lid;
}

// ================= 256x256 8-phase GEMM core (round-2 proven: 88.2us, 0 conflicts) =================
// BM=BN=256, BK=64, 512 threads = 8 waves (2M x 4N), per-wave C = 2 x (64x64).
// Eight [128][64] LDS buffers (128B rows -> row-invariant banks + chunk-XOR = conflict-free).
//   A{d}{a}: K-tile parity d, M-half a.   B{d}{h}: parity d, N-half h.
// Per phase: 8 ds_read_b128 + stage of ONE 16KB buffer (2 gl_lds16) + [gate] +
// barrier + lgkmcnt(0) + setprio(1) + 16 MFMA + setprio(0) + barrier.
// vmcnt(2) gates only at ph4/ph8 -- never vmcnt(0) in the loop.

#define GATE2  asm volatile("s_waitcnt vmcnt(2)" ::: "memory")
#define NOGATE do {} while (0)

#define STAGE(DST, G, H, KT) do {                                              \
    gl_lds16((G) + (size_t)((H) * 128 + rs0) * DIM + (KT) * 64 + cs0 * 8,      \
             (DST) + wid * 512);                                               \
    gl_lds16((G) + (size_t)((H) * 128 + 64 + rs0) * DIM + (KT) * 64 + cs0 * 8, \
             (DST) + 4096 + wid * 512);                                        \
} while (0)

#define PHASE(Ad, Bd, AA, KS, STAGE_STMT, GATE_STMT) do {                      \
    bf16x8 af_[4], bf_[4];                                                     \
    _Pragma("unroll")                                                          \
    for (int i_ = 0; i_ < 4; i_++) {                                           \
        af_[i_] = *(const bf16x8*)((Ad) + aRdBase + i_ * 1024 + xorv[KS]);     \
        bf_[i_] = *(const bf16x8*)((Bd) + bRdBase + i_ * 1024 + xorv[KS]);     \
    }                                                                          \
    STAGE_STMT;                                                                \
    GATE_STMT;                                                                 \
    __builtin_amdgcn_s_barrier();                                              \
    asm volatile("s_waitcnt lgkmcnt(0)" ::: "memory");                         \
    __builtin_amdgcn_sched_barrier(0);                                         \
    __builtin_amdgcn_s_setprio(1);                                             \
    _Pragma("unroll")                                                          \
    for (int i_ = 0; i_ < 4; i_++)                                             \
        _Pragma("unroll")                                                      \
        for (int n_ = 0; n_ < 4; n_++)                                         \
            acc[AA][i_][n_] = __builtin_amdgcn_mfma_f32_16x16x32_bf16(         \
                af_[i_], bf_[n_], acc[AA][i_][n_], 0, 0, 0);                   \
    __builtin_amdgcn_s_setprio(0);                                             \
    __builtin_amdgcn_s_barrier();                                              \
} while (0)

__device__ __forceinline__ void gemm256_core(const bf16* __restrict__ Ag,
                                             const bf16* __restrict__ Bg,
                                             f32x4 (&acc)[2][4][4]) {
    __shared__ __align__(16) bf16 A00[128 * 64], A01[128 * 64], A10[128 * 64], A11[128 * 64];
    __shared__ __align__(16) bf16 B00[128 * 64], B01[128 * 64], B10[128 * 64], B11[128 * 64];

    const int tid  = threadIdx.x;
    const int wid  = tid >> 6, lane = tid & 63;
    const int quad = lane >> 4, r16 = lane & 15;
    const int wm = wid & 1, wn = wid >> 1;

    const int rs0 = tid >> 3;
    const int cs0 = (tid & 7) ^ (rs0 & 7);

    const int aRdBase = (wm * 64 + r16) * 64;
    const int bRdBase = ((wn & 1) * 64 + r16) * 64;
    const int xorv[2] = { (quad ^ (r16 & 7)) * 8, ((4 + quad) ^ (r16 & 7)) * 8 };

    const bf16* Bd0 = (wn & 2) ? B01 : B00;   // wave's N-half, parity 0
    const bf16* Bd1 = (wn & 2) ? B11 : B10;   // wave's N-half, parity 1

    // prologue: full tile0 + A-half0 of tile1 (5 units = 10 loads)
    STAGE(A00, Ag, 0, 0);
    STAGE(A01, Ag, 1, 0);
    STAGE(B00, Bg, 0, 0);
    STAGE(B01, Bg, 1, 0);
    STAGE(A10, Ag, 0, 1);
    GATE2;                                  // tile0 landed; A10<-t1 may fly
    __builtin_amdgcn_s_barrier();

#pragma unroll 1
    for (int it = 0; it < 8; ++it) {        // 2 K-tiles / iter, NT = 16
        const int t1 = 2 * it + 1;
        int t2 = 2 * it + 2; if (t2 > 15) t2 = 15;
        int t3 = 2 * it + 3; if (t3 > 15) t3 = 15;
        PHASE(A00, Bd0, 0, 0, STAGE(A11, Ag, 1, t1), NOGATE);
        PHASE(A00, Bd0, 0, 1, STAGE(B10, Bg, 0, t1), NOGATE);
        PHASE(A01, Bd0, 1, 0, STAGE(B11, Bg, 1, t1), NOGATE);
        PHASE(A01, Bd0, 1, 1, STAGE(A00, Ag, 0, t2), GATE2);   // t1 units landed
        PHASE(A10, Bd1, 0, 0, STAGE(A01, Ag, 1, t2), NOGATE);
        PHASE(A10, Bd1, 0, 1, STAGE(B00, Bg, 0, t2), NOGATE);
        PHASE(A11, Bd1, 1, 0, STAGE(B01, Bg, 1, t2), NOGATE);
        PHASE(A11, Bd1, 1, 1, STAGE(A10, Ag, 0, t3), GATE2);   // t2 units landed
    }
}

// ---------------- QKV GEMM with fused QKNorm + partial 2D-RoPE epilogue ----------------
__global__ __launch_bounds__(512) void gemm_qkv(const bf16* __restrict__ A,
                                                const bf16* __restrict__ Bw,
                                                bf16* __restrict__ out,
                                                const float* __restrict__ qw,
                                                const float* __restrict__ kw,
                                                const float2* __restrict__ ctab) {
    const int nwg = (MROWS / 256) * (NQKV / 256);   // 396
    int wg = xcd_swizzle(blockIdx.x, nwg);
    const int bm = wg / 6, bn = wg - bm * 6;

    f32x4 acc[2][4][4];
#pragma unroll
    for (int a = 0; a < 2; a++)
#pragma unroll
        for (int i = 0; i < 4; i++)
#pragma unroll
            for (int n = 0; n < 4; n++) acc[a][i][n] = (f32x4){0.f, 0.f, 0.f, 0.f};

    gemm256_core(A + (size_t)bm * 256 * DIM, Bw + (size_t)bn * 256 * DIM, acc);

    const int tid  = threadIdx.x;
    const int wid  = tid >> 6, lane = tid & 63;
    const int quad = lane >> 4, r16 = lane & 15;
    const int wm = wid & 1, wn = wid >> 1;
    const int colbase = bn * 256 + wn * 64;          // 64-aligned -> one head per wave
    const int rowb    = bm * 256 + wm * 64;

    if (bn < 5) {
        const float* w = (bn < 4) ? qw : kw;
        float wreg[4];
#pragma unroll
        for (int n = 0; n < 4; n++) wreg[n] = w[n * 16 + r16];
#pragma unroll
        for (int a = 0; a < 2; a++)
#pragma unroll
            for (int i = 0; i < 4; i++)
#pragma unroll
                for (int r = 0; r < 4; r++) {
                    float ss = 0.f;
#pragma unroll
                    for (int n = 0; n < 4; n++) ss += acc[a][i][n][r] * acc[a][i][n][r];
                    ss += __shfl_xor(ss, 1, 64);
                    ss += __shfl_xor(ss, 2, 64);
                    ss += __shfl_xor(ss, 4, 64);
                    ss += __shfl_xor(ss, 8, 64);
                    float rms = rsqrtf(ss * (1.f / 64.f) + 1e-6f);
                    float xv[4];
#pragma unroll
                    for (int n = 0; n < 4; n++) xv[n] = acc[a][i][n][r] * rms * wreg[n];
                    int gm = rowb + a * 128 + i * 16 + quad * 4 + r;
                    int s = gm % SLEN;
                    if (s < NZ) {   // partial 2D RoPE; pairs (n, n+2) are lane-local
                        float2 cs0 = ctab[s * 32 + r16];
                        float2 cs1 = ctab[s * 32 + 16 + r16];
                        float a0 = xv[0] * cs0.x - xv[2] * cs0.y;
                        float a2 = xv[2] * cs0.x + xv[0] * cs0.y;
                        float a1 = xv[1] * cs1.x - xv[3] * cs1.y;
                        float a3 = xv[3] * cs1.x + xv[1] * cs1.y;
                        xv[0] = a0; xv[1] = a1; xv[2] = a2; xv[3] = a3;
                    }
                    size_t rowoff = (size_t)gm * NQKV + colbase + r16;
#pragma unroll
                    for (int n = 0; n < 4; n++) out[rowoff + n * 16] = (bf16)xv[n];
                }
    } else {
#pragma unroll
        for (int a = 0; a < 2; a++)
#pragma unroll
            for (int i = 0; i < 4; i++)
#pragma unroll
                for (int r = 0; r < 4; r++) {
                    int gm = rowb + a * 128 + i * 16 + quad * 4 + r;
                    size_t rowoff = (size_t)gm * NQKV + colbase + r16;
#pragma unroll
                    for (int n = 0; n < 4; n++) out[rowoff + n * 16] = (bf16)acc[a][i][n][r];
                }
    }
}

// ================= 128x128 2-phase core for gemm_bt (3-4 blocks/CU, no tail) =================
#define GEMM_STAGE_PTRS(Mptr, tileRow, K, P)                                   \
    const bf16* P[4];                                                          \
    {                                                                          \
        _Pragma("unroll")                                                      \
        for (int k = 0; k < 4; k++) {                                          \
            int s = k * 256 + tid;                                             \
            int r = s >> 3, cp = s & 7;                                        \
            int c = cp ^ (r & 7);                                              \
            P[k] = (Mptr) + (size_t)((tileRow) + r) * (K) + c * 8;             \
        }                                                                      \
    }

__device__ __forceinline__ int swz(int row, int chunk) {   // LDS element offset
    return row * 64 + ((chunk ^ (row & 7)) * 8);
}

__global__ __launch_bounds__(256) void gemm_bt(const bf16* __restrict__ A,
                                               const bf16* __restrict__ Bw,
                                               float* __restrict__ Cout) {
    __shared__ __align__(16) bf16 As[128 * 64];
    __shared__ __align__(16) bf16 Bs[128 * 64];
    const int tid  = threadIdx.x;
    const int wid  = tid >> 6, lane = tid & 63;
    const int quad = lane >> 4, r16 = lane & 15;
    const int bid = blockIdx.x;
    const int g = bid / 32, rr = bid - g * 32;
    const int bm = g * 4 + (rr & 3), bn = rr >> 2;
    const int wm = wid & 1, wn = wid >> 1;

    GEMM_STAGE_PTRS(A,  bm * 128, DIM, Ap)
    GEMM_STAGE_PTRS(Bw, bn * 128, DIM, Bp)

    f32x4 acc[4][4];
#pragma unroll
    for (int i = 0; i < 4; i++)
#pragma unroll
        for (int j = 0; j < 4; j++) acc[i][j] = (f32x4){0.f, 0.f, 0.f, 0.f};

    for (int k0 = 0; k0 < DIM; k0 += 64) {
        __syncthreads();
#pragma unroll
        for (int k = 0; k < 4; k++) {
            gl_lds16(Ap[k] + k0, As + (k * 256 + wid * 64) * 8);
            gl_lds16(Bp[k] + k0, Bs + (k * 256 + wid * 64) * 8);
        }
        __syncthreads();
#pragma unroll
        for (int ks = 0; ks < 2; ks++) {
            bf16x8 a[4], b[4];
#pragma unroll
            for (int i = 0; i < 4; i++) {
                a[i] = *(const bf16x8*)&As[swz(wm * 64 + i * 16 + r16, ks * 4 + quad)];
                b[i] = *(const bf16x8*)&Bs[swz(wn * 64 + i * 16 + r16, ks * 4 + quad)];
            }
#pragma unroll
            for (int i = 0; i < 4; i++)
#pragma unroll
                for (int j = 0; j < 4; j++)
                    acc[i][j] = __builtin_amdgcn_mfma_f32_16x16x32_bf16(a[i], b[j], acc[i][j], 0, 0, 0);
        }
    }

#pragma unroll
    for (int i = 0; i < 4; i++)
#pragma unroll
        for (int j = 0; j < 4; j++)
#pragma unroll
            for (int r = 0; r < 4; r++) {
                int gm = bm * 128 + wm * 64 + i * 16 + quad * 4 + r;
                int gn = bn * 128 + wn * 64 + j * 16 + r16;
                Cout[(size_t)gm * DIM + gn] = acc[i][j][r];
            }
}

// ---------------- V transpose: qkv V region -> vt[(bt,kv)][d][key], zero-padded to 288 keys ----------------
__global__ __launch_bounds__(256) void vtrans_kernel(const bf16* __restrict__ qkv,
                                                     bf16* __restrict__ vt) {
    __shared__ bf16 Ls[64 * 272];
    const int tid = threadIdx.x;
    const int b = blockIdx.x, bt = b >> 2, kv = b & 3;
    const int part = tid >> 5;      // 0..7 (dim octet)
    const int rr   = tid & 31;      // row within pass
#pragma unroll
    for (int pass = 0; pass < 9; ++pass) {
        int row = pass * 32 + rr;
        if (row < SLEN) {
            bf16x8 v = *(const bf16x8*)(qkv + (size_t)(bt * SLEN + row) * NQKV + 1280 + kv * 64 + part * 8);
#pragma unroll
            for (int j = 0; j < 8; j++) Ls[(part * 8 + j) * 272 + row] = v[j];
        }
    }
    __syncthreads();
    const int d = tid >> 2, seg = tid & 3;
    size_t obase = ((size_t)b * 64 + d) * VPAD;
#pragma unroll
    for (int m = 0; m < 9; ++m) {
        int col = seg * 72 + m * 8;
        bf16x8 o;
#pragma unroll
        for (int j = 0; j < 8; j++) {
            int s = col + j;
            o[j] = (s < SLEN) ? Ls[d * 272 + s] : (bf16)0.f;
        }
        *(bf16x8*)(vt + obase + col) = o;
    }
}

// ---------------- attention v5: swapped-QK 32x32 MFMA, in-register softmax (T12) ----------------
// One wave per (32-q-row tile, head, bt). S^T = mfma(K,Q): lane owns q = lane&31;
// per chunk (32 keys): 4 QK mfma + softcap(16 vals) + 8 cvt_pk + 4 permlane32_swap
// -> P A-frags in-register (ZERO LDS traffic) + 4 PV mfma. lsum per-lane, one
// shfl_xor(32) at the end. Row map (m74/m101): col=lane&31, row=(r&3)+8*(r>>2)+4*hi.
__global__ __launch_bounds__(256) void attn_kernel(const bf16* __restrict__ qkv,
                                                   const bf16* __restrict__ vt,
                                                   bf16* __restrict__ aout) {
    __shared__ float invL[4][32];
    const int tid = threadIdx.x;
    const int wid = tid >> 6, lane = tid & 63;
    const int l31 = lane & 31, hi = lane >> 5;
    const int qp = blockIdx.x;           // 0..8 (9 tiles of 32 q-rows = 288)
    const int kv = blockIdx.y, bt = blockIdx.z;
    const int h = kv * 4 + wid;

    // Q as B-operand: B[k=d][n=q]; lane: q = l31, k = s*16 + hi*8 + reg
    int q0 = qp * 32 + l31;
    int qcl = q0 < SLEN ? q0 : SLEN - 1;
    const bf16* qbase = qkv + (size_t)(bt * SLEN + qcl) * NQKV + h * HD + hi * 8;
    bf16x8 qb[4];
#pragma unroll
    for (int s = 0; s < 4; s++) qb[s] = *(const bf16x8*)(qbase + s * 16);

    const bf16* kbase = qkv + (size_t)bt * SLEN * NQKV + 1024 + kv * HD + hi * 8;
    const bf16* vbase = vt + (size_t)(bt * 4 + kv) * HD * VPAD;

    // K as A-operand: A[row=key][k=d]; lane: key = c*32 + l31 (clamped load, masked use)
    bf16x8 nka[4];
    {
        const bf16* kp = kbase + (size_t)l31 * NQKV;
#pragma unroll
        for (int s = 0; s < 4; s++) nka[s] = *(const bf16x8*)(kp + s * 16);
    }

    f32x16 oacc[2];
#pragma unroll
    for (int r = 0; r < 16; r++) { oacc[0][r] = 0.f; oacc[1][r] = 0.f; }
    float lsum = 0.f;

    for (int c = 0; c < 9; ++c) {
        bf16x8 ka[4];
#pragma unroll
        for (int s = 0; s < 4; s++) ka[s] = nka[s];
        if (c < 8) {   // prefetch next chunk's K
            int key = (c + 1) * 32 + l31;
            int kc = key < SLEN ? key : SLEN - 1;
            const bf16* kp = kbase + (size_t)kc * NQKV;
#pragma unroll
            for (int s = 0; s < 4; s++) nka[s] = *(const bf16x8*)(kp + s * 16);
        }
        // V as B-operand: B[k=key][n=d]; lane: d = dt*32+l31, k = st*16 + hi*8 + reg
        bf16x8 vb[2][2];
#pragma unroll
        for (int dt = 0; dt < 2; dt++)
#pragma unroll
            for (int st = 0; st < 2; st++)
                vb[dt][st] = *(const bf16x8*)(vbase + (size_t)(dt * 32 + l31) * VPAD + c * 32 + st * 16 + hi * 8);

        // QK^T (swapped): D[key][q]
        f32x16 sacc;
#pragma unroll
        for (int r = 0; r < 16; r++) sacc[r] = 0.f;
#pragma unroll
        for (int s = 0; s < 4; s++)
            sacc = __builtin_amdgcn_mfma_f32_32x32x16_bf16(ka[s], qb[s], sacc, 0, 0, 0);

        // softcap: p = exp(50*tanh(sc*SCALE/50)); mask key >= SLEN; lsum in f32
        float p[16];
#pragma unroll
        for (int r = 0; r < 16; ++r) {
            int key = c * 32 + (r & 3) + 8 * (r >> 2) + 4 * hi;
            float sc = sacc[r];
            float z = sc * 0.0025f;                       // sc*SCALE/50
            float z2 = z * z;
            float poly = fmaf(z2, fmaf(z2, 0.133333333f, -0.333333333f), 1.f);
            float pv = exp2f(sc * 0.18033688f * poly);    // 50*log2e*z*poly
            pv = (key < SLEN) ? pv : 0.f;
            p[r] = pv;
            lsum += pv;
        }
        // pack to bf16 A-frags via cvt_pk + permlane32_swap (T12):
        //   own keys (4hi-grouped) -> A-frag keys (8hi-grouped), derived per m74 layout:
        //   swap(wA,wC) -> frag u32[0], u32[2]; swap(wB,wD) -> u32[1], u32[3].
#pragma unroll
        for (int st = 0; st < 2; st++) {
            u32 wA, wB, wC, wD;
            asm("v_cvt_pk_bf16_f32 %0, %1, %2" : "=v"(wA) : "v"(p[st*8+0]), "v"(p[st*8+1]));
            asm("v_cvt_pk_bf16_f32 %0, %1, %2" : "=v"(wB) : "v"(p[st*8+2]), "v"(p[st*8+3]));
            asm("v_cvt_pk_bf16_f32 %0, %1, %2" : "=v"(wC) : "v"(p[st*8+4]), "v"(p[st*8+5]));
            asm("v_cvt_pk_bf16_f32 %0, %1, %2" : "=v"(wD) : "v"(p[st*8+6]), "v"(p[st*8+7]));
            asm volatile("v_permlane32_swap_b32 %0, %1" : "+v"(wA), "+v"(wC));
            asm volatile("v_permlane32_swap_b32 %0, %1" : "+v"(wB), "+v"(wD));
            union { u32 u[4]; bf16x8 v; } pa;
            pa.u[0] = wA; pa.u[1] = wB; pa.u[2] = wC; pa.u[3] = wD;
#pragma unroll
            for (int dt = 0; dt < 2; dt++)
                oacc[dt] = __builtin_amdgcn_mfma_f32_32x32x16_bf16(pa.v, vb[dt][st], oacc[dt], 0, 0, 0);
        }
    }

    // finalize: lsum over 32 keys-half split lives across hi-pair
    lsum += __shfl_xor(lsum, 32, 64);
    invL[wid][l31] = 1.f / lsum;           // per-wave LDS, wave-coherent
#pragma unroll
    for (int r = 0; r < 16; ++r) {
        int qloc = (r & 3) + 8 * (r >> 2) + 4 * hi;
        int q = qp * 32 + qloc;
        if (q < SLEN) {
            float inv = invL[wid][qloc];
            size_t base = (size_t)(bt * SLEN + q) * (NH * HD) + h * HD + l31;
            aout[base]      = (bf16)(oacc[0][r] * inv);
            aout[base + 32] = (bf16)(oacc[1][r] * inv);
        }
    }
}

// ---------------- launcher ----------------
extern "C" void kernel_launch(void* const* d_in, const int* in_sizes, int n_in,
                              void* d_out, int out_size, void* d_ws, size_t ws_size,
                              hipStream_t stream) {
    const float* x   = (const float*)d_in[0];
    const float* wq  = (const float*)d_in[1];
    const float* wk  = (const float*)d_in[2];
    const float* wv  = (const float*)d_in[3];
    const float* wo  = (const float*)d_in[4];
    const float* qnw = (const float*)d_in[5];
    const float* knw = (const float*)d_in[6];

    bf16* xbf  = (bf16*)d_ws;                        // 16896x1024 (reused as aout)
    bf16* wcat = xbf  + (size_t)MROWS * DIM;         // 1536x1024  [wq;wk;wv]
    bf16* wobf = wcat + (size_t)NQKV * DIM;          // 1024x1024
    bf16* qkv  = wobf + (size_t)DIM * DIM;           // 16896x1536
    bf16* vt   = qkv  + (size_t)MROWS * NQKV;        // 256x64x288
    float2* ctab = (float2*)(vt + (size_t)BTOT * NKV * HD * VPAD);  // 256x32
    bf16* aout = xbf;                                // xbf dead after gemm_qkv

    prep_misc<<<2592, 256, 0, stream>>>(wq, wk, wv, wo, wcat, wobf, ctab);
    cvt_f32_bf16<<<(MROWS * DIM) / 1024, 256, 0, stream>>>(x, xbf, MROWS * DIM);

    gemm_qkv<<<(MROWS / 256) * (NQKV / 256), 512, 0, stream>>>(xbf, wcat, qkv, qnw, knw, ctab);
    vtrans_kernel<<<BTOT * NKV, 256, 0, stream>>>(qkv, vt);
    attn_kernel<<<dim3(9, NKV, BTOT), 256, 0, stream>>>(qkv, vt, aout);
    gemm_bt<<<(MROWS / 128) * (DIM / 128), 256, 0, stream>>>(aout, wobf, (float*)d_out);
}

// Round 5
// 335.317 us; speedup vs baseline: 1.2627x; 1.0097x over previous
//
#include <hip/hip_runtime.h>

typedef __bf16 bf16;
typedef __bf16 bf16x8 __attribute__((ext_vector_type(8)));
typedef float  f32x4  __attribute__((ext_vector_type(4)));
typedef float  f32x16 __attribute__((ext_vector_type(16)));
typedef unsigned int u32;

#define DIM   1024
#define NH    16
#define NKV   4
#define HD    64
#define SLEN  264
#define BTOT  64            // B*T
#define MROWS (BTOT * SLEN) // 16896
#define NQKV  1536          // 1024 q + 256 k + 256 v
#define NZ    256
#define VPAD  288           // padded key dim of vt

// ---------------- async global->LDS (wave-uniform LDS base + lane*16; global src is per-lane) ----------------
__device__ __forceinline__ void gl_lds16(const bf16* g, bf16* l) {
    __builtin_amdgcn_global_load_lds((__attribute__((address_space(1))) void*)(g),
                                     (__attribute__((address_space(3))) void*)(l),
                                     16, 0, 0);
}

// ---------------- f32 -> bf16 converter for x ----------------
__global__ void cvt_f32_bf16(const float* __restrict__ src, bf16* __restrict__ dst, int n) {
    int i = (blockIdx.x * 256 + threadIdx.x) * 4;
    if (i < n) {
        float4 v = *(const float4*)(src + i);
        dst[i + 0] = (bf16)v.x; dst[i + 1] = (bf16)v.y;
        dst[i + 2] = (bf16)v.z; dst[i + 3] = (bf16)v.w;
    }
}

// ---------------- fused prep: wcat cvt (1536 blk) + wo cvt (1024 blk) + rope tab (32 blk) ----------------
__global__ void prep_misc(const float* __restrict__ wq, const float* __restrict__ wk,
                          const float* __restrict__ wv, const float* __restrict__ wo,
                          bf16* __restrict__ wcat, bf16* __restrict__ wobf,
                          float2* __restrict__ ctab) {
    int b = blockIdx.x, tid = threadIdx.x;
    if (b < 1536) {
        int i = (b * 256 + tid) * 4;
        const float* src; int off;
        if (i < 1024 * 1024)      { src = wq; off = i; }
        else if (i < 1280 * 1024) { src = wk; off = i - 1024 * 1024; }
        else                      { src = wv; off = i - 1280 * 1024; }
        float4 v = *(const float4*)(src + off);
        wcat[i + 0] = (bf16)v.x; wcat[i + 1] = (bf16)v.y;
        wcat[i + 2] = (bf16)v.z; wcat[i + 3] = (bf16)v.w;
    } else if (b < 2560) {
        int i = ((b - 1536) * 256 + tid) * 4;
        float4 v = *(const float4*)(wo + i);
        wobf[i + 0] = (bf16)v.x; wobf[i + 1] = (bf16)v.y;
        wobf[i + 2] = (bf16)v.z; wobf[i + 3] = (bf16)v.w;
    } else {
        int i = (b - 2560) * 256 + tid;    // 8192 = 256 x 32
        int s = i >> 5, d = i & 31;
        const float LN1 = 0.5756462732485115f;    // ln(10000)/16
        float pos = (d < 16) ? (float)(s >> 4) : (float)(s & 15);
        float ang = pos * expf(-(float)(d & 15) * LN1);
        float sn, cs; sincosf(ang, &sn, &cs);
        ctab[i] = make_float2(cs, sn);
    }
}

// bijective XCD-chunked block swizzle (m204): contiguous wg-chunks per XCD
__device__ __forceinline__ int xcd_swizzle(int orig, int nwg) {
    int q = nwg >> 3, r = nwg & 7;
    int xcd = orig & 7, lid = orig >> 3;
    return (xcd < r ? xcd * (q + 1) : r * (q + 1) + (xcd - r) * q) + lid;
}

// ================= 256x256 8-phase GEMM core (round-2 proven: 88.2us, 0 conflicts) =================
#define GATE2  asm volatile("s_waitcnt vmcnt(2)" ::: "memory")
#define NOGATE do {} while (0)

#define STAGE(DST, G, H, KT) do {                                              \
    gl_lds16((G) + (size_t)((H) * 128 + rs0) * DIM + (KT) * 64 + cs0 * 8,      \
             (DST) + wid * 512);                                               \
    gl_lds16((G) + (size_t)((H) * 128 + 64 + rs0) * DIM + (KT) * 64 + cs0 * 8, \
             (DST) + 4096 + wid * 512);                                        \
} while (0)

#define PHASE(Ad, Bd, AA, KS, STAGE_STMT, GATE_STMT) do {                      \
    bf16x8 af_[4], bf_[4];                                                     \
    _Pragma("unroll")                                                          \
    for (int i_ = 0; i_ < 4; i_++) {                                           \
        af_[i_] = *(const bf16x8*)((Ad) + aRdBase + i_ * 1024 + xorv[KS]);     \
        bf_[i_] = *(const bf16x8*)((Bd) + bRdBase + i_ * 1024 + xorv[KS]);     \
    }                                                                          \
    STAGE_STMT;                                                                \
    GATE_STMT;                                                                 \
    __builtin_amdgcn_s_barrier();                                              \
    asm volatile("s_waitcnt lgkmcnt(0)" ::: "memory");                         \
    __builtin_amdgcn_sched_barrier(0);                                         \
    __builtin_amdgcn_s_setprio(1);                                             \
    _Pragma("unroll")                                                          \
    for (int i_ = 0; i_ < 4; i_++)                                             \
        _Pragma("unroll")                                                      \
        for (int n_ = 0; n_ < 4; n_++)                                         \
            acc[AA][i_][n_] = __builtin_amdgcn_mfma_f32_16x16x32_bf16(         \
                af_[i_], bf_[n_], acc[AA][i_][n_], 0, 0, 0);                   \
    __builtin_amdgcn_s_setprio(0);                                             \
    __builtin_amdgcn_s_barrier();                                              \
} while (0)

__device__ __forceinline__ void gemm256_core(const bf16* __restrict__ Ag,
                                             const bf16* __restrict__ Bg,
                                             f32x4 (&acc)[2][4][4]) {
    __shared__ __align__(16) bf16 A00[128 * 64], A01[128 * 64], A10[128 * 64], A11[128 * 64];
    __shared__ __align__(16) bf16 B00[128 * 64], B01[128 * 64], B10[128 * 64], B11[128 * 64];

    const int tid  = threadIdx.x;
    const int wid  = tid >> 6, lane = tid & 63;
    const int quad = lane >> 4, r16 = lane & 15;
    const int wm = wid & 1, wn = wid >> 1;

    const int rs0 = tid >> 3;
    const int cs0 = (tid & 7) ^ (rs0 & 7);

    const int aRdBase = (wm * 64 + r16) * 64;
    const int bRdBase = ((wn & 1) * 64 + r16) * 64;
    const int xorv[2] = { (quad ^ (r16 & 7)) * 8, ((4 + quad) ^ (r16 & 7)) * 8 };

    const bf16* Bd0 = (wn & 2) ? B01 : B00;   // wave's N-half, parity 0
    const bf16* Bd1 = (wn & 2) ? B11 : B10;   // wave's N-half, parity 1

    STAGE(A00, Ag, 0, 0);
    STAGE(A01, Ag, 1, 0);
    STAGE(B00, Bg, 0, 0);
    STAGE(B01, Bg, 1, 0);
    STAGE(A10, Ag, 0, 1);
    GATE2;                                  // tile0 landed; A10<-t1 may fly
    __builtin_amdgcn_s_barrier();

#pragma unroll 1
    for (int it = 0; it < 8; ++it) {        // 2 K-tiles / iter, NT = 16
        const int t1 = 2 * it + 1;
        int t2 = 2 * it + 2; if (t2 > 15) t2 = 15;
        int t3 = 2 * it + 3; if (t3 > 15) t3 = 15;
        PHASE(A00, Bd0, 0, 0, STAGE(A11, Ag, 1, t1), NOGATE);
        PHASE(A00, Bd0, 0, 1, STAGE(B10, Bg, 0, t1), NOGATE);
        PHASE(A01, Bd0, 1, 0, STAGE(B11, Bg, 1, t1), NOGATE);
        PHASE(A01, Bd0, 1, 1, STAGE(A00, Ag, 0, t2), GATE2);   // t1 units landed
        PHASE(A10, Bd1, 0, 0, STAGE(A01, Ag, 1, t2), NOGATE);
        PHASE(A10, Bd1, 0, 1, STAGE(B00, Bg, 0, t2), NOGATE);
        PHASE(A11, Bd1, 1, 0, STAGE(B01, Bg, 1, t2), NOGATE);
        PHASE(A11, Bd1, 1, 1, STAGE(A10, Ag, 0, t3), GATE2);   // t2 units landed
    }
}

// ---------------- QKV GEMM with fused QKNorm + partial 2D-RoPE epilogue ----------------
__global__ __launch_bounds__(512) void gemm_qkv(const bf16* __restrict__ A,
                                                const bf16* __restrict__ Bw,
                                                bf16* __restrict__ out,
                                                const float* __restrict__ qw,
                                                const float* __restrict__ kw,
                                                const float2* __restrict__ ctab) {
    const int nwg = (MROWS / 256) * (NQKV / 256);   // 396
    int wg = xcd_swizzle(blockIdx.x, nwg);
    const int bm = wg / 6, bn = wg - bm * 6;

    f32x4 acc[2][4][4];
#pragma unroll
    for (int a = 0; a < 2; a++)
#pragma unroll
        for (int i = 0; i < 4; i++)
#pragma unroll
            for (int n = 0; n < 4; n++) acc[a][i][n] = (f32x4){0.f, 0.f, 0.f, 0.f};

    gemm256_core(A + (size_t)bm * 256 * DIM, Bw + (size_t)bn * 256 * DIM, acc);

    const int tid  = threadIdx.x;
    const int wid  = tid >> 6, lane = tid & 63;
    const int quad = lane >> 4, r16 = lane & 15;
    const int wm = wid & 1, wn = wid >> 1;
    const int colbase = bn * 256 + wn * 64;          // 64-aligned -> one head per wave
    const int rowb    = bm * 256 + wm * 64;

    if (bn < 5) {
        const float* w = (bn < 4) ? qw : kw;
        float wreg[4];
#pragma unroll
        for (int n = 0; n < 4; n++) wreg[n] = w[n * 16 + r16];
#pragma unroll
        for (int a = 0; a < 2; a++)
#pragma unroll
            for (int i = 0; i < 4; i++)
#pragma unroll
                for (int r = 0; r < 4; r++) {
                    float ss = 0.f;
#pragma unroll
                    for (int n = 0; n < 4; n++) ss += acc[a][i][n][r] * acc[a][i][n][r];
                    ss += __shfl_xor(ss, 1, 64);
                    ss += __shfl_xor(ss, 2, 64);
                    ss += __shfl_xor(ss, 4, 64);
                    ss += __shfl_xor(ss, 8, 64);
                    float rms = rsqrtf(ss * (1.f / 64.f) + 1e-6f);
                    float xv[4];
#pragma unroll
                    for (int n = 0; n < 4; n++) xv[n] = acc[a][i][n][r] * rms * wreg[n];
                    int gm = rowb + a * 128 + i * 16 + quad * 4 + r;
                    int s = gm % SLEN;
                    if (s < NZ) {   // partial 2D RoPE; pairs (n, n+2) are lane-local
                        float2 cs0 = ctab[s * 32 + r16];
                        float2 cs1 = ctab[s * 32 + 16 + r16];
                        float a0 = xv[0] * cs0.x - xv[2] * cs0.y;
                        float a2 = xv[2] * cs0.x + xv[0] * cs0.y;
                        float a1 = xv[1] * cs1.x - xv[3] * cs1.y;
                        float a3 = xv[3] * cs1.x + xv[1] * cs1.y;
                        xv[0] = a0; xv[1] = a1; xv[2] = a2; xv[3] = a3;
                    }
                    size_t rowoff = (size_t)gm * NQKV + colbase + r16;
#pragma unroll
                    for (int n = 0; n < 4; n++) out[rowoff + n * 16] = (bf16)xv[n];
                }
    } else {
#pragma unroll
        for (int a = 0; a < 2; a++)
#pragma unroll
            for (int i = 0; i < 4; i++)
#pragma unroll
                for (int r = 0; r < 4; r++) {
                    int gm = rowb + a * 128 + i * 16 + quad * 4 + r;
                    size_t rowoff = (size_t)gm * NQKV + colbase + r16;
#pragma unroll
                    for (int n = 0; n < 4; n++) out[rowoff + n * 16] = (bf16)acc[a][i][n][r];
                }
    }
}

// ================= 128x128 2-phase core for gemm_bt (3-4 blocks/CU, no tail) =================
#define GEMM_STAGE_PTRS(Mptr, tileRow, K, P)                                   \
    const bf16* P[4];                                                          \
    {                                                                          \
        _Pragma("unroll")                                                      \
        for (int k = 0; k < 4; k++) {                                          \
            int s = k * 256 + tid;                                             \
            int r = s >> 3, cp = s & 7;                                        \
            int c = cp ^ (r & 7);                                              \
            P[k] = (Mptr) + (size_t)((tileRow) + r) * (K) + c * 8;             \
        }                                                                      \
    }

__device__ __forceinline__ int swz(int row, int chunk) {   // LDS element offset
    return row * 64 + ((chunk ^ (row & 7)) * 8);
}

__global__ __launch_bounds__(256) void gemm_bt(const bf16* __restrict__ A,
                                               const bf16* __restrict__ Bw,
                                               float* __restrict__ Cout) {
    __shared__ __align__(16) bf16 As[128 * 64];
    __shared__ __align__(16) bf16 Bs[128 * 64];
    const int tid  = threadIdx.x;
    const int wid  = tid >> 6, lane = tid & 63;
    const int quad = lane >> 4, r16 = lane & 15;
    const int bid = blockIdx.x;
    const int g = bid / 32, rr = bid - g * 32;
    const int bm = g * 4 + (rr & 3), bn = rr >> 2;
    const int wm = wid & 1, wn = wid >> 1;

    GEMM_STAGE_PTRS(A,  bm * 128, DIM, Ap)
    GEMM_STAGE_PTRS(Bw, bn * 128, DIM, Bp)

    f32x4 acc[4][4];
#pragma unroll
    for (int i = 0; i < 4; i++)
#pragma unroll
        for (int j = 0; j < 4; j++) acc[i][j] = (f32x4){0.f, 0.f, 0.f, 0.f};

    for (int k0 = 0; k0 < DIM; k0 += 64) {
        __syncthreads();
#pragma unroll
        for (int k = 0; k < 4; k++) {
            gl_lds16(Ap[k] + k0, As + (k * 256 + wid * 64) * 8);
            gl_lds16(Bp[k] + k0, Bs + (k * 256 + wid * 64) * 8);
        }
        __syncthreads();
#pragma unroll
        for (int ks = 0; ks < 2; ks++) {
            bf16x8 a[4], b[4];
#pragma unroll
            for (int i = 0; i < 4; i++) {
                a[i] = *(const bf16x8*)&As[swz(wm * 64 + i * 16 + r16, ks * 4 + quad)];
                b[i] = *(const bf16x8*)&Bs[swz(wn * 64 + i * 16 + r16, ks * 4 + quad)];
            }
#pragma unroll
            for (int i = 0; i < 4; i++)
#pragma unroll
                for (int j = 0; j < 4; j++)
                    acc[i][j] = __builtin_amdgcn_mfma_f32_16x16x32_bf16(a[i], b[j], acc[i][j], 0, 0, 0);
        }
    }

#pragma unroll
    for (int i = 0; i < 4; i++)
#pragma unroll
        for (int j = 0; j < 4; j++)
#pragma unroll
            for (int r = 0; r < 4; r++) {
                int gm = bm * 128 + wm * 64 + i * 16 + quad * 4 + r;
                int gn = bn * 128 + wn * 64 + j * 16 + r16;
                Cout[(size_t)gm * DIM + gn] = acc[i][j][r];
            }
}

// ---------------- V transpose: qkv V region -> vt[(bt,kv)][d][key], zero-padded to 288 keys ----------------
__global__ __launch_bounds__(256) void vtrans_kernel(const bf16* __restrict__ qkv,
                                                     bf16* __restrict__ vt) {
    __shared__ bf16 Ls[64 * 272];
    const int tid = threadIdx.x;
    const int b = blockIdx.x, bt = b >> 2, kv = b & 3;
    const int part = tid >> 5;      // 0..7 (dim octet)
    const int rr   = tid & 31;      // row within pass
#pragma unroll
    for (int pass = 0; pass < 9; ++pass) {
        int row = pass * 32 + rr;
        if (row < SLEN) {
            bf16x8 v = *(const bf16x8*)(qkv + (size_t)(bt * SLEN + row) * NQKV + 1280 + kv * 64 + part * 8);
#pragma unroll
            for (int j = 0; j < 8; j++) Ls[(part * 8 + j) * 272 + row] = v[j];
        }
    }
    __syncthreads();
    const int d = tid >> 2, seg = tid & 3;
    size_t obase = ((size_t)b * 64 + d) * VPAD;
#pragma unroll
    for (int m = 0; m < 9; ++m) {
        int col = seg * 72 + m * 8;
        bf16x8 o;
#pragma unroll
        for (int j = 0; j < 8; j++) {
            int s = col + j;
            o[j] = (s < SLEN) ? Ls[d * 272 + s] : (bf16)0.f;
        }
        *(bf16x8*)(vt + obase + col) = o;
    }
}

// ---------------- attention v6: block-cooperative LDS K/V staging + in-register softmax ----------------
// 5 stages of 64 keys. Per stage: K tile [64 key][64 d] + V tile [64 d][64 key],
// each 8KB, staged ONCE per block (4 waves share) via 4 gl_lds16/thread from
// coalesced 16B sources. GEMM-proven 128B-row chunk-XOR LDS layout (0-conflict).
// Compute pipeline identical to v5 (swapped QK^T 32x32, in-reg softcap,
// cvt_pk+permlane pack, PV from [d][key]-major V). One __syncthreads per stage
// (its vmcnt drain = landing guarantee); stage p+1 issued before compute of p.
__global__ __launch_bounds__(256) void attn_kernel(const bf16* __restrict__ qkv,
                                                   const bf16* __restrict__ vt,
                                                   bf16* __restrict__ aout) {
    __shared__ __align__(16) bf16 Kb[2][64 * 64];   // [buf][key][d], chunk-XOR swizzled
    __shared__ __align__(16) bf16 Vb[2][64 * 64];   // [buf][d][key], chunk-XOR swizzled
    __shared__ float invL[4][32];

    const int tid = threadIdx.x;
    const int wid = tid >> 6, lane = tid & 63;
    const int l31 = lane & 31, hi = lane >> 5;
    const int qp = blockIdx.x;           // 0..8 (9 tiles of 32 q-rows = 288)
    const int kv = blockIdx.y, bt = blockIdx.z;
    const int h = kv * 4 + wid;

    // Q as B-operand (unchanged from v5): lane q = l31, k = s*16 + hi*8 + reg
    int q0 = qp * 32 + l31;
    int qcl = q0 < SLEN ? q0 : SLEN - 1;
    const bf16* qbase = qkv + (size_t)(bt * SLEN + qcl) * NQKV + h * HD + hi * 8;
    bf16x8 qb[4];
#pragma unroll
    for (int s = 0; s < 4; s++) qb[s] = *(const bf16x8*)(qbase + s * 16);

    // staging thread constants: slots tid (rows 0..31) and tid+256 (rows 32..63);
    // row&7 identical for both -> same logical chunk kc0.
    const int r0  = tid >> 3;                       // 0..31
    const int r1  = r0 + 32;                        // 32..63
    const int kc0 = (tid & 7) ^ (r0 & 7);           // logical 8-elem chunk
    const bf16* kg = qkv + (size_t)bt * SLEN * NQKV + 1024 + kv * 64 + kc0 * 8;  // + keyrow*NQKV
    const bf16* vg = vt + (size_t)(bt * 4 + kv) * HD * VPAD;                      // + d*VPAD + off

#define STAGEP(PB, P64) do {                                                     \
    int kr0 = (P64) + r0; if (kr0 > SLEN - 1) kr0 = SLEN - 1;                    \
    int kr1 = (P64) + r1; if (kr1 > SLEN - 1) kr1 = SLEN - 1;                    \
    gl_lds16(kg + (size_t)kr0 * NQKV, &Kb[PB][tid * 8]);                         \
    gl_lds16(kg + (size_t)kr1 * NQKV, &Kb[PB][(tid + 256) * 8]);                 \
    int vo = (P64) + kc0 * 8; if (vo > VPAD - 8) vo = VPAD - 8;                  \
    gl_lds16(vg + (size_t)r0 * VPAD + vo, &Vb[PB][tid * 8]);                     \
    gl_lds16(vg + (size_t)r1 * VPAD + vo, &Vb[PB][(tid + 256) * 8]);             \
} while (0)

    // frag read offsets (elements); key/d low-3-bits == l31&7 in all cases
    const int xorb = l31 & 7;
    int koff[4];
#pragma unroll
    for (int s = 0; s < 4; s++) koff[s] = l31 * 64 + (((s * 2 + hi) ^ xorb) * 8);

    f32x16 oacc[2];
#pragma unroll
    for (int r = 0; r < 16; r++) { oacc[0][r] = 0.f; oacc[1][r] = 0.f; }
    float lsum = 0.f;

    STAGEP(0, 0);
    __syncthreads();

#pragma unroll 1
    for (int p = 0; p < 5; ++p) {
        const int pb = p & 1;
        if (p < 4) STAGEP(pb ^ 1, (p + 1) * 64);
        const int hmax = (p == 4) ? 1 : 2;   // keys 288..319 fully masked -> skip
        for (int hh = 0; hh < hmax; ++hh) {
            const bf16* Kp = &Kb[pb][hh * 2048];
            // QK^T (swapped): D[key][q]
            f32x16 sacc;
#pragma unroll
            for (int r = 0; r < 16; r++) sacc[r] = 0.f;
#pragma unroll
            for (int s = 0; s < 4; s++) {
                bf16x8 ka = *(const bf16x8*)(Kp + koff[s]);
                sacc = __builtin_amdgcn_mfma_f32_32x32x16_bf16(ka, qb[s], sacc, 0, 0, 0);
            }
            // softcap: arg = sc*(A + B t + C t^2), t = sc^2  (Horner form of
            // 50*log2e*tanh-poly(sc*SCALE/50)); mask keys >= SLEN
            const int keyb = p * 64 + hh * 32;
            float pr[16];
#pragma unroll
            for (int r = 0; r < 16; ++r) {
                float sc = sacc[r];
                float t = sc * sc;
                float w = fmaf(t, 9.392546e-13f, -3.7570183e-7f);
                w = fmaf(t, w, 0.18033688f);
                float pv = exp2f(sc * w);
                int key = keyb + (r & 3) + 8 * (r >> 2) + 4 * hi;
                pv = (key < SLEN) ? pv : 0.f;
                pr[r] = pv;
                lsum += pv;
            }
            // pack to bf16 A-frags via cvt_pk + permlane32_swap (layout verified in v5)
#pragma unroll
            for (int st = 0; st < 2; st++) {
                u32 wA, wB, wC, wD;
                asm("v_cvt_pk_bf16_f32 %0, %1, %2" : "=v"(wA) : "v"(pr[st*8+0]), "v"(pr[st*8+1]));
                asm("v_cvt_pk_bf16_f32 %0, %1, %2" : "=v"(wB) : "v"(pr[st*8+2]), "v"(pr[st*8+3]));
                asm("v_cvt_pk_bf16_f32 %0, %1, %2" : "=v"(wC) : "v"(pr[st*8+4]), "v"(pr[st*8+5]));
                asm("v_cvt_pk_bf16_f32 %0, %1, %2" : "=v"(wD) : "v"(pr[st*8+6]), "v"(pr[st*8+7]));
                asm volatile("v_permlane32_swap_b32 %0, %1" : "+v"(wA), "+v"(wC));
                asm volatile("v_permlane32_swap_b32 %0, %1" : "+v"(wB), "+v"(wD));
                union { u32 u[4]; bf16x8 v; } pa;
                pa.u[0] = wA; pa.u[1] = wB; pa.u[2] = wC; pa.u[3] = wD;
#pragma unroll
                for (int dt = 0; dt < 2; dt++) {
                    bf16x8 vbf = *(const bf16x8*)(&Vb[pb][(dt * 32 + l31) * 64 +
                                         (((hh * 4 + st * 2 + hi) ^ xorb) * 8)]);
                    oacc[dt] = __builtin_amdgcn_mfma_f32_32x32x16_bf16(pa.v, vbf, oacc[dt], 0, 0, 0);
                }
            }
        }
        if (p < 4) __syncthreads();   // drains gl_lds (vmcnt) -> buf pb^1 ready; all reads of pb done
    }
#undef STAGEP

    // finalize: lsum split lives across hi-pair
    lsum += __shfl_xor(lsum, 32, 64);
    invL[wid][l31] = 1.f / lsum;           // per-wave LDS, wave-coherent
#pragma unroll
    for (int r = 0; r < 16; ++r) {
        int qloc = (r & 3) + 8 * (r >> 2) + 4 * hi;
        int q = qp * 32 + qloc;
        if (q < SLEN) {
            float inv = invL[wid][qloc];
            size_t base = (size_t)(bt * SLEN + q) * (NH * HD) + h * HD + l31;
            aout[base]      = (bf16)(oacc[0][r] * inv);
            aout[base + 32] = (bf16)(oacc[1][r] * inv);
        }
    }
}

// ---------------- launcher ----------------
extern "C" void kernel_launch(void* const* d_in, const int* in_sizes, int n_in,
                              void* d_out, int out_size, void* d_ws, size_t ws_size,
                              hipStream_t stream) {
    const float* x   = (const float*)d_in[0];
    const float* wq  = (const float*)d_in[1];
    const float* wk  = (const float*)d_in[2];
    const float* wv  = (const float*)d_in[3];
    const float* wo  = (const float*)d_in[4];
    const float* qnw = (const float*)d_in[5];
    const float* knw = (const float*)d_in[6];

    bf16* xbf  = (bf16*)d_ws;                        // 16896x1024 (reused as aout)
    bf16* wcat = xbf  + (size_t)MROWS * DIM;         // 1536x1024  [wq;wk;wv]
    bf16* wobf = wcat + (size_t)NQKV * DIM;          // 1024x1024
    bf16* qkv  = wobf + (size_t)DIM * DIM;           // 16896x1536
    bf16* vt   = qkv  + (size_t)MROWS * NQKV;        // 256x64x288
    float2* ctab = (float2*)(vt + (size_t)BTOT * NKV * HD * VPAD);  // 256x32
    bf16* aout = xbf;                                // xbf dead after gemm_qkv

    prep_misc<<<2592, 256, 0, stream>>>(wq, wk, wv, wo, wcat, wobf, ctab);
    cvt_f32_bf16<<<(MROWS * DIM) / 1024, 256, 0, stream>>>(x, xbf, MROWS * DIM);

    gemm_qkv<<<(MROWS / 256) * (NQKV / 256), 512, 0, stream>>>(xbf, wcat, qkv, qnw, knw, ctab);
    vtrans_kernel<<<BTOT * NKV, 256, 0, stream>>>(qkv, vt);
    attn_kernel<<<dim3(9, NKV, BTOT), 256, 0, stream>>>(qkv, vt, aout);
    gemm_bt<<<(MROWS / 128) * (DIM / 128), 256, 0, stream>>>(aout, wobf, (float*)d_out);
}

// Round 6
// 322.851 us; speedup vs baseline: 1.3114x; 1.0386x over previous
//
#include <hip/hip_runtime.h>

typedef __bf16 bf16;
typedef __bf16 bf16x4 __attribute__((ext_vector_type(4)));
typedef __bf16 bf16x8 __attribute__((ext_vector_type(8)));
typedef float  f32x4  __attribute__((ext_vector_type(4)));
typedef float  f32x16 __attribute__((ext_vector_type(16)));
typedef unsigned int u32;

#define DIM   1024
#define NH    16
#define NKV   4
#define HD    64
#define SLEN  264
#define BTOT  64            // B*T
#define MROWS (BTOT * SLEN) // 16896
#define NQKV  1536          // 1024 q + 256 k + 256 v
#define NZ    256
#define VPAD  288           // padded key dim of vt

// ---------------- async global->LDS (wave-uniform LDS base + lane*16; global src is per-lane) ----------------
__device__ __forceinline__ void gl_lds16(const bf16* g, bf16* l) {
    __builtin_amdgcn_global_load_lds((__attribute__((address_space(1))) void*)(g),
                                     (__attribute__((address_space(3))) void*)(l),
                                     16, 0, 0);
}

// ---------------- fused prep: x cvt (16896 blk) + wcat (1536) + wo (1024) + rope (32) + vt pad (192) ----------------
__global__ void prep_misc(const float* __restrict__ x,
                          const float* __restrict__ wq, const float* __restrict__ wk,
                          const float* __restrict__ wv, const float* __restrict__ wo,
                          bf16* __restrict__ xbf, bf16* __restrict__ wcat,
                          bf16* __restrict__ wobf, float2* __restrict__ ctab,
                          bf16* __restrict__ vt) {
    int b = blockIdx.x, tid = threadIdx.x;
    if (b < 16896) {                        // x: f32 -> bf16 (16896*1024 elems)
        int i = (b * 256 + tid) * 4;
        float4 v = *(const float4*)(x + i);
        xbf[i + 0] = (bf16)v.x; xbf[i + 1] = (bf16)v.y;
        xbf[i + 2] = (bf16)v.z; xbf[i + 3] = (bf16)v.w;
        return;
    }
    int b2 = b - 16896;
    if (b2 < 1536) {                        // wcat = [wq;wk;wv] bf16
        int i = (b2 * 256 + tid) * 4;
        const float* src; int off;
        if (i < 1024 * 1024)      { src = wq; off = i; }
        else if (i < 1280 * 1024) { src = wk; off = i - 1024 * 1024; }
        else                      { src = wv; off = i - 1280 * 1024; }
        float4 v = *(const float4*)(src + off);
        wcat[i + 0] = (bf16)v.x; wcat[i + 1] = (bf16)v.y;
        wcat[i + 2] = (bf16)v.z; wcat[i + 3] = (bf16)v.w;
    } else if (b2 < 2560) {                 // wo bf16
        int i = ((b2 - 1536) * 256 + tid) * 4;
        float4 v = *(const float4*)(wo + i);
        wobf[i + 0] = (bf16)v.x; wobf[i + 1] = (bf16)v.y;
        wobf[i + 2] = (bf16)v.z; wobf[i + 3] = (bf16)v.w;
    } else if (b2 < 2592) {                 // rope cos/sin table: 256 x 32
        int i = (b2 - 2560) * 256 + tid;
        int s = i >> 5, d = i & 31;
        const float LN1 = 0.5756462732485115f;    // ln(10000)/16
        float pos = (d < 16) ? (float)(s >> 4) : (float)(s & 15);
        float ang = pos * expf(-(float)(d & 15) * LN1);
        float sn, cs; sincosf(ang, &sn, &cs);
        ctab[i] = make_float2(cs, sn);
    } else {                                // vt zero-pad: 16384 rows x cols 264..287
        int idx = (b2 - 2592) * 256 + tid;  // < 49152 = 16384 * 3
        int row = idx / 3, c = idx - row * 3;
        bf16x8 z = {};
        *(bf16x8*)(vt + (size_t)row * VPAD + 264 + c * 8) = z;
    }
}

// bijective XCD-chunked block swizzle (m204): contiguous wg-chunks per XCD
__device__ __forceinline__ int xcd_swizzle(int orig, int nwg) {
    int q = nwg >> 3, r = nwg & 7;
    int xcd = orig & 7, lid = orig >> 3;
    return (xcd < r ? xcd * (q + 1) : r * (q + 1) + (xcd - r) * q) + lid;
}

// ================= 256x256 8-phase GEMM core (round-2 proven: 88.2us, 0 conflicts) =================
#define GATE2  asm volatile("s_waitcnt vmcnt(2)" ::: "memory")
#define NOGATE do {} while (0)

#define STAGE(DST, G, H, KT) do {                                              \
    gl_lds16((G) + (size_t)((H) * 128 + rs0) * DIM + (KT) * 64 + cs0 * 8,      \
             (DST) + wid * 512);                                               \
    gl_lds16((G) + (size_t)((H) * 128 + 64 + rs0) * DIM + (KT) * 64 + cs0 * 8, \
             (DST) + 4096 + wid * 512);                                        \
} while (0)

#define PHASE(Ad, Bd, AA, KS, STAGE_STMT, GATE_STMT) do {                      \
    bf16x8 af_[4], bf_[4];                                                     \
    _Pragma("unroll")                                                          \
    for (int i_ = 0; i_ < 4; i_++) {                                           \
        af_[i_] = *(const bf16x8*)((Ad) + aRdBase + i_ * 1024 + xorv[KS]);     \
        bf_[i_] = *(const bf16x8*)((Bd) + bRdBase + i_ * 1024 + xorv[KS]);     \
    }                                                                          \
    STAGE_STMT;                                                                \
    GATE_STMT;                                                                 \
    __builtin_amdgcn_s_barrier();                                              \
    asm volatile("s_waitcnt lgkmcnt(0)" ::: "memory");                         \
    __builtin_amdgcn_sched_barrier(0);                                         \
    __builtin_amdgcn_s_setprio(1);                                             \
    _Pragma("unroll")                                                          \
    for (int i_ = 0; i_ < 4; i_++)                                             \
        _Pragma("unroll")                                                      \
        for (int n_ = 0; n_ < 4; n_++)                                         \
            acc[AA][i_][n_] = __builtin_amdgcn_mfma_f32_16x16x32_bf16(         \
                af_[i_], bf_[n_], acc[AA][i_][n_], 0, 0, 0);                   \
    __builtin_amdgcn_s_setprio(0);                                             \
    __builtin_amdgcn_s_barrier();                                              \
} while (0)

__device__ __forceinline__ void gemm256_core(const bf16* __restrict__ Ag,
                                             const bf16* __restrict__ Bg,
                                             f32x4 (&acc)[2][4][4]) {
    __shared__ __align__(16) bf16 A00[128 * 64], A01[128 * 64], A10[128 * 64], A11[128 * 64];
    __shared__ __align__(16) bf16 B00[128 * 64], B01[128 * 64], B10[128 * 64], B11[128 * 64];

    const int tid  = threadIdx.x;
    const int wid  = tid >> 6, lane = tid & 63;
    const int quad = lane >> 4, r16 = lane & 15;
    const int wm = wid & 1, wn = wid >> 1;

    const int rs0 = tid >> 3;
    const int cs0 = (tid & 7) ^ (rs0 & 7);

    const int aRdBase = (wm * 64 + r16) * 64;
    const int bRdBase = ((wn & 1) * 64 + r16) * 64;
    const int xorv[2] = { (quad ^ (r16 & 7)) * 8, ((4 + quad) ^ (r16 & 7)) * 8 };

    const bf16* Bd0 = (wn & 2) ? B01 : B00;   // wave's N-half, parity 0
    const bf16* Bd1 = (wn & 2) ? B11 : B10;   // wave's N-half, parity 1

    STAGE(A00, Ag, 0, 0);
    STAGE(A01, Ag, 1, 0);
    STAGE(B00, Bg, 0, 0);
    STAGE(B01, Bg, 1, 0);
    STAGE(A10, Ag, 0, 1);
    GATE2;                                  // tile0 landed; A10<-t1 may fly
    __builtin_amdgcn_s_barrier();

#pragma unroll 1
    for (int it = 0; it < 8; ++it) {        // 2 K-tiles / iter, NT = 16
        const int t1 = 2 * it + 1;
        int t2 = 2 * it + 2; if (t2 > 15) t2 = 15;
        int t3 = 2 * it + 3; if (t3 > 15) t3 = 15;
        PHASE(A00, Bd0, 0, 0, STAGE(A11, Ag, 1, t1), NOGATE);
        PHASE(A00, Bd0, 0, 1, STAGE(B10, Bg, 0, t1), NOGATE);
        PHASE(A01, Bd0, 1, 0, STAGE(B11, Bg, 1, t1), NOGATE);
        PHASE(A01, Bd0, 1, 1, STAGE(A00, Ag, 0, t2), GATE2);   // t1 units landed
        PHASE(A10, Bd1, 0, 0, STAGE(A01, Ag, 1, t2), NOGATE);
        PHASE(A10, Bd1, 0, 1, STAGE(B00, Bg, 0, t2), NOGATE);
        PHASE(A11, Bd1, 1, 0, STAGE(B01, Bg, 1, t2), NOGATE);
        PHASE(A11, Bd1, 1, 1, STAGE(A10, Ag, 0, t3), GATE2);   // t2 units landed
    }
}

// ---------------- QKV GEMM: fused QKNorm + partial 2D-RoPE (Q,K) and fused V-transpose (V) ----------------
// C[M,1536] = A[M,1024] @ W[1536,1024]^T. Each wave's 64 cols == one head.
// bn<4: Q (norm+rope -> qkv). bn==4: K (norm+rope -> qkv). bn==5: V written
// TRANSPOSED directly to vt[(bt,kv)][d][key] (vtrans kernel eliminated);
// V region of qkv is never written (dead).
__global__ __launch_bounds__(512) void gemm_qkv(const bf16* __restrict__ A,
                                                const bf16* __restrict__ Bw,
                                                bf16* __restrict__ out,
                                                bf16* __restrict__ vt,
                                                const float* __restrict__ qw,
                                                const float* __restrict__ kw,
                                                const float2* __restrict__ ctab) {
    const int nwg = (MROWS / 256) * (NQKV / 256);   // 396
    int wg = xcd_swizzle(blockIdx.x, nwg);
    const int bm = wg / 6, bn = wg - bm * 6;

    f32x4 acc[2][4][4];
#pragma unroll
    for (int a = 0; a < 2; a++)
#pragma unroll
        for (int i = 0; i < 4; i++)
#pragma unroll
            for (int n = 0; n < 4; n++) acc[a][i][n] = (f32x4){0.f, 0.f, 0.f, 0.f};

    gemm256_core(A + (size_t)bm * 256 * DIM, Bw + (size_t)bn * 256 * DIM, acc);

    const int tid  = threadIdx.x;
    const int wid  = tid >> 6, lane = tid & 63;
    const int quad = lane >> 4, r16 = lane & 15;
    const int wm = wid & 1, wn = wid >> 1;
    const int colbase = bn * 256 + wn * 64;          // 64-aligned -> one head per wave
    const int rowb    = bm * 256 + wm * 64;

    if (bn < 5) {
        const float* w = (bn < 4) ? qw : kw;
        float wreg[4];
#pragma unroll
        for (int n = 0; n < 4; n++) wreg[n] = w[n * 16 + r16];
#pragma unroll
        for (int a = 0; a < 2; a++)
#pragma unroll
            for (int i = 0; i < 4; i++)
#pragma unroll
                for (int r = 0; r < 4; r++) {
                    float ss = 0.f;
#pragma unroll
                    for (int n = 0; n < 4; n++) ss += acc[a][i][n][r] * acc[a][i][n][r];
                    ss += __shfl_xor(ss, 1, 64);
                    ss += __shfl_xor(ss, 2, 64);
                    ss += __shfl_xor(ss, 4, 64);
                    ss += __shfl_xor(ss, 8, 64);
                    float rms = rsqrtf(ss * (1.f / 64.f) + 1e-6f);
                    float xv[4];
#pragma unroll
                    for (int n = 0; n < 4; n++) xv[n] = acc[a][i][n][r] * rms * wreg[n];
                    int gm = rowb + a * 128 + i * 16 + quad * 4 + r;
                    int s = gm % SLEN;
                    if (s < NZ) {   // partial 2D RoPE; pairs (n, n+2) are lane-local
                        float2 cs0 = ctab[s * 32 + r16];
                        float2 cs1 = ctab[s * 32 + 16 + r16];
                        float a0 = xv[0] * cs0.x - xv[2] * cs0.y;
                        float a2 = xv[2] * cs0.x + xv[0] * cs0.y;
                        float a1 = xv[1] * cs1.x - xv[3] * cs1.y;
                        float a3 = xv[3] * cs1.x + xv[1] * cs1.y;
                        xv[0] = a0; xv[1] = a1; xv[2] = a2; xv[3] = a3;
                    }
                    size_t rowoff = (size_t)gm * NQKV + colbase + r16;
#pragma unroll
                    for (int n = 0; n < 4; n++) out[rowoff + n * 16] = (bf16)xv[n];
                }
    } else {
        // V: transposed write to vt[(bt, kv=wn)][d = n*16+r16][key], 8B stores.
        // gm0 % 4 == 0 and SLEN % 4 == 0 -> the 4 consecutive keys share bt
        // and start 8B-aligned.
#pragma unroll
        for (int a = 0; a < 2; a++)
#pragma unroll
            for (int i = 0; i < 4; i++) {
                int gm0 = rowb + a * 128 + i * 16 + quad * 4;
                int btv = gm0 / SLEN;
                int key0 = gm0 - btv * SLEN;
                bf16* vbase = vt + (size_t)(btv * 4 + wn) * 64 * VPAD + key0;
#pragma unroll
                for (int n = 0; n < 4; n++) {
                    bf16x4 v4;
                    v4[0] = (bf16)acc[a][i][n][0];
                    v4[1] = (bf16)acc[a][i][n][1];
                    v4[2] = (bf16)acc[a][i][n][2];
                    v4[3] = (bf16)acc[a][i][n][3];
                    *(bf16x4*)(vbase + (size_t)(n * 16 + r16) * VPAD) = v4;
                }
            }
    }
}

// ================= 128x128 2-phase core for gemm_bt (3-4 blocks/CU, no tail) =================
#define GEMM_STAGE_PTRS(Mptr, tileRow, K, P)                                   \
    const bf16* P[4];                                                          \
    {                                                                          \
        _Pragma("unroll")                                                      \
        for (int k = 0; k < 4; k++) {                                          \
            int s = k * 256 + tid;                                             \
            int r = s >> 3, cp = s & 7;                                        \
            int c = cp ^ (r & 7);                                              \
            P[k] = (Mptr) + (size_t)((tileRow) + r) * (K) + c * 8;             \
        }                                                                      \
    }

__device__ __forceinline__ int swz(int row, int chunk) {   // LDS element offset
    return row * 64 + ((chunk ^ (row & 7)) * 8);
}

__global__ __launch_bounds__(256) void gemm_bt(const bf16* __restrict__ A,
                                               const bf16* __restrict__ Bw,
                                               float* __restrict__ Cout) {
    __shared__ __align__(16) bf16 As[128 * 64];
    __shared__ __align__(16) bf16 Bs[128 * 64];
    const int tid  = threadIdx.x;
    const int wid  = tid >> 6, lane = tid & 63;
    const int quad = lane >> 4, r16 = lane & 15;
    const int bid = blockIdx.x;
    const int g = bid / 32, rr = bid - g * 32;
    const int bm = g * 4 + (rr & 3), bn = rr >> 2;
    const int wm = wid & 1, wn = wid >> 1;

    GEMM_STAGE_PTRS(A,  bm * 128, DIM, Ap)
    GEMM_STAGE_PTRS(Bw, bn * 128, DIM, Bp)

    f32x4 acc[4][4];
#pragma unroll
    for (int i = 0; i < 4; i++)
#pragma unroll
        for (int j = 0; j < 4; j++) acc[i][j] = (f32x4){0.f, 0.f, 0.f, 0.f};

    for (int k0 = 0; k0 < DIM; k0 += 64) {
        __syncthreads();
#pragma unroll
        for (int k = 0; k < 4; k++) {
            gl_lds16(Ap[k] + k0, As + (k * 256 + wid * 64) * 8);
            gl_lds16(Bp[k] + k0, Bs + (k * 256 + wid * 64) * 8);
        }
        __syncthreads();
#pragma unroll
        for (int ks = 0; ks < 2; ks++) {
            bf16x8 a[4], b[4];
#pragma unroll
            for (int i = 0; i < 4; i++) {
                a[i] = *(const bf16x8*)&As[swz(wm * 64 + i * 16 + r16, ks * 4 + quad)];
                b[i] = *(const bf16x8*)&Bs[swz(wn * 64 + i * 16 + r16, ks * 4 + quad)];
            }
#pragma unroll
            for (int i = 0; i < 4; i++)
#pragma unroll
                for (int j = 0; j < 4; j++)
                    acc[i][j] = __builtin_amdgcn_mfma_f32_16x16x32_bf16(a[i], b[j], acc[i][j], 0, 0, 0);
        }
    }

#pragma unroll
    for (int i = 0; i < 4; i++)
#pragma unroll
        for (int j = 0; j < 4; j++)
#pragma unroll
            for (int r = 0; r < 4; r++) {
                int gm = bm * 128 + wm * 64 + i * 16 + quad * 4 + r;
                int gn = bn * 128 + wn * 64 + j * 16 + r16;
                Cout[(size_t)gm * DIM + gn] = acc[i][j][r];
            }
}

// ---------------- attention v6: block-cooperative LDS K/V staging + in-register softmax ----------------
__global__ __launch_bounds__(256) void attn_kernel(const bf16* __restrict__ qkv,
                                                   const bf16* __restrict__ vt,
                                                   bf16* __restrict__ aout) {
    __shared__ __align__(16) bf16 Kb[2][64 * 64];   // [buf][key][d], chunk-XOR swizzled
    __shared__ __align__(16) bf16 Vb[2][64 * 64];   // [buf][d][key], chunk-XOR swizzled
    __shared__ float invL[4][32];

    const int tid = threadIdx.x;
    const int wid = tid >> 6, lane = tid & 63;
    const int l31 = lane & 31, hi = lane >> 5;
    const int qp = blockIdx.x;           // 0..8 (9 tiles of 32 q-rows = 288)
    const int kv = blockIdx.y, bt = blockIdx.z;
    const int h = kv * 4 + wid;

    // Q as B-operand: lane q = l31, k = s*16 + hi*8 + reg
    int q0 = qp * 32 + l31;
    int qcl = q0 < SLEN ? q0 : SLEN - 1;
    const bf16* qbase = qkv + (size_t)(bt * SLEN + qcl) * NQKV + h * HD + hi * 8;
    bf16x8 qb[4];
#pragma unroll
    for (int s = 0; s < 4; s++) qb[s] = *(const bf16x8*)(qbase + s * 16);

    const int r0  = tid >> 3;                       // 0..31
    const int r1  = r0 + 32;                        // 32..63
    const int kc0 = (tid & 7) ^ (r0 & 7);           // logical 8-elem chunk
    const bf16* kg = qkv + (size_t)bt * SLEN * NQKV + 1024 + kv * 64 + kc0 * 8;  // + keyrow*NQKV
    const bf16* vg = vt + (size_t)(bt * 4 + kv) * HD * VPAD;                      // + d*VPAD + off

#define STAGEP(PB, P64) do {                                                     \
    int kr0 = (P64) + r0; if (kr0 > SLEN - 1) kr0 = SLEN - 1;                    \
    int kr1 = (P64) + r1; if (kr1 > SLEN - 1) kr1 = SLEN - 1;                    \
    gl_lds16(kg + (size_t)kr0 * NQKV, &Kb[PB][tid * 8]);                         \
    gl_lds16(kg + (size_t)kr1 * NQKV, &Kb[PB][(tid + 256) * 8]);                 \
    int vo = (P64) + kc0 * 8; if (vo > VPAD - 8) vo = VPAD - 8;                  \
    gl_lds16(vg + (size_t)r0 * VPAD + vo, &Vb[PB][tid * 8]);                     \
    gl_lds16(vg + (size_t)r1 * VPAD + vo, &Vb[PB][(tid + 256) * 8]);             \
} while (0)

    const int xorb = l31 & 7;
    int koff[4];
#pragma unroll
    for (int s = 0; s < 4; s++) koff[s] = l31 * 64 + (((s * 2 + hi) ^ xorb) * 8);

    f32x16 oacc[2];
#pragma unroll
    for (int r = 0; r < 16; r++) { oacc[0][r] = 0.f; oacc[1][r] = 0.f; }
    float lsum = 0.f;

    STAGEP(0, 0);
    __syncthreads();

#pragma unroll 1
    for (int p = 0; p < 5; ++p) {
        const int pb = p & 1;
        if (p < 4) STAGEP(pb ^ 1, (p + 1) * 64);
        const int hmax = (p == 4) ? 1 : 2;   // keys 288..319 fully masked -> skip
        for (int hh = 0; hh < hmax; ++hh) {
            const bf16* Kp = &Kb[pb][hh * 2048];
            f32x16 sacc;
#pragma unroll
            for (int r = 0; r < 16; r++) sacc[r] = 0.f;
#pragma unroll
            for (int s = 0; s < 4; s++) {
                bf16x8 ka = *(const bf16x8*)(Kp + koff[s]);
                sacc = __builtin_amdgcn_mfma_f32_32x32x16_bf16(ka, qb[s], sacc, 0, 0, 0);
            }
            const int keyb = p * 64 + hh * 32;
            float pr[16];
#pragma unroll
            for (int r = 0; r < 16; ++r) {
                float sc = sacc[r];
                float t = sc * sc;
                float w = fmaf(t, 9.392546e-13f, -3.7570183e-7f);
                w = fmaf(t, w, 0.18033688f);
                float pv = exp2f(sc * w);
                int key = keyb + (r & 3) + 8 * (r >> 2) + 4 * hi;
                pv = (key < SLEN) ? pv : 0.f;
                pr[r] = pv;
                lsum += pv;
            }
#pragma unroll
            for (int st = 0; st < 2; st++) {
                u32 wA, wB, wC, wD;
                asm("v_cvt_pk_bf16_f32 %0, %1, %2" : "=v"(wA) : "v"(pr[st*8+0]), "v"(pr[st*8+1]));
                asm("v_cvt_pk_bf16_f32 %0, %1, %2" : "=v"(wB) : "v"(pr[st*8+2]), "v"(pr[st*8+3]));
                asm("v_cvt_pk_bf16_f32 %0, %1, %2" : "=v"(wC) : "v"(pr[st*8+4]), "v"(pr[st*8+5]));
                asm("v_cvt_pk_bf16_f32 %0, %1, %2" : "=v"(wD) : "v"(pr[st*8+6]), "v"(pr[st*8+7]));
                asm volatile("v_permlane32_swap_b32 %0, %1" : "+v"(wA), "+v"(wC));
                asm volatile("v_permlane32_swap_b32 %0, %1" : "+v"(wB), "+v"(wD));
                union { u32 u[4]; bf16x8 v; } pa;
                pa.u[0] = wA; pa.u[1] = wB; pa.u[2] = wC; pa.u[3] = wD;
#pragma unroll
                for (int dt = 0; dt < 2; dt++) {
                    bf16x8 vbf = *(const bf16x8*)(&Vb[pb][(dt * 32 + l31) * 64 +
                                         (((hh * 4 + st * 2 + hi) ^ xorb) * 8)]);
                    oacc[dt] = __builtin_amdgcn_mfma_f32_32x32x16_bf16(pa.v, vbf, oacc[dt], 0, 0, 0);
                }
            }
        }
        if (p < 4) __syncthreads();   // drains gl_lds (vmcnt) -> buf pb^1 ready; all reads of pb done
    }
#undef STAGEP

    lsum += __shfl_xor(lsum, 32, 64);
    invL[wid][l31] = 1.f / lsum;           // per-wave LDS, wave-coherent
#pragma unroll
    for (int r = 0; r < 16; ++r) {
        int qloc = (r & 3) + 8 * (r >> 2) + 4 * hi;
        int q = qp * 32 + qloc;
        if (q < SLEN) {
            float inv = invL[wid][qloc];
            size_t base = (size_t)(bt * SLEN + q) * (NH * HD) + h * HD + l31;
            aout[base]      = (bf16)(oacc[0][r] * inv);
            aout[base + 32] = (bf16)(oacc[1][r] * inv);
        }
    }
}

// ---------------- launcher (4 kernels) ----------------
extern "C" void kernel_launch(void* const* d_in, const int* in_sizes, int n_in,
                              void* d_out, int out_size, void* d_ws, size_t ws_size,
                              hipStream_t stream) {
    const float* x   = (const float*)d_in[0];
    const float* wq  = (const float*)d_in[1];
    const float* wk  = (const float*)d_in[2];
    const float* wv  = (const float*)d_in[3];
    const float* wo  = (const float*)d_in[4];
    const float* qnw = (const float*)d_in[5];
    const float* knw = (const float*)d_in[6];

    bf16* xbf  = (bf16*)d_ws;                        // 16896x1024 (reused as aout)
    bf16* wcat = xbf  + (size_t)MROWS * DIM;         // 1536x1024  [wq;wk;wv]
    bf16* wobf = wcat + (size_t)NQKV * DIM;          // 1024x1024
    bf16* qkv  = wobf + (size_t)DIM * DIM;           // 16896x1536 (V region unused)
    bf16* vt   = qkv  + (size_t)MROWS * NQKV;        // 256x64x288
    float2* ctab = (float2*)(vt + (size_t)BTOT * NKV * HD * VPAD);  // 256x32
    bf16* aout = xbf;                                // xbf dead after gemm_qkv

    prep_misc<<<16896 + 1536 + 1024 + 32 + 192, 256, 0, stream>>>(
        x, wq, wk, wv, wo, xbf, wcat, wobf, ctab, vt);

    gemm_qkv<<<(MROWS / 256) * (NQKV / 256), 512, 0, stream>>>(xbf, wcat, qkv, vt, qnw, knw, ctab);
    attn_kernel<<<dim3(9, NKV, BTOT), 256, 0, stream>>>(qkv, vt, aout);
    gemm_bt<<<(MROWS / 128) * (DIM / 128), 256, 0, stream>>>(aout, wobf, (float*)d_out);
}